// Round 7
// baseline (528.786 us; speedup 1.0000x reference)
//
#include <hip/hip_runtime.h>
#include <hip/hip_bf16.h>
#include <cstdint>

// Problem constants (from reference): B,T,E,C,I_E,O = 4,2048,8,512,512,4096
constexpr int NB = 4;
constexpr int NT = 2048;
constexpr int NE = 8;
constexpr int NC = 512;
constexpr int NI = 512;
constexpr int NO = 4096;
constexpr int NEC = NE * NC;  // 4096 (stage-2 K)

typedef __attribute__((ext_vector_type(8))) short short8;
typedef __attribute__((ext_vector_type(8))) unsigned short ushort8;
typedef __attribute__((ext_vector_type(4))) float f32x4;

// f32 -> bf16 round-to-nearest-even
__device__ __forceinline__ unsigned short f2bf(float f) {
  unsigned int u = __builtin_bit_cast(unsigned int, f);
  u += 0x7FFFu + ((u >> 16) & 1u);
  return (unsigned short)(u >> 16);
}

__device__ __forceinline__ ushort8 cvt8(float4 a, float4 b) {
  ushort8 v;
  v[0] = f2bf(a.x); v[1] = f2bf(a.y); v[2] = f2bf(a.z); v[3] = f2bf(a.w);
  v[4] = f2bf(b.x); v[5] = f2bf(b.y); v[6] = f2bf(b.z); v[7] = f2bf(b.w);
  return v;
}

// XOR-swizzle: byte offset within a [row][64B] tile. Involution on bits 4-5.
// Fragment read lanes 0..15 (rows r..r+15, fixed kb) -> 8 distinct 16B slots
// per 8-row stripe -> 2-way (free) bank aliasing.
__device__ __forceinline__ int lds_byte(int row, int kbyte) {
  return (row * 64 + kbyte) ^ ((row & 6) << 3);
}

// async global(16B) -> LDS, wave-uniform LDS base + lane*16 (HW semantics)
__device__ __forceinline__ void gload_lds16(const void* g, void* lds) {
  __builtin_amdgcn_global_load_lds(
      (const __attribute__((address_space(1))) unsigned int*)g,
      (__attribute__((address_space(3))) unsigned int*)lds, 16, 0, 0);
}

// ===========================================================================
// FAST PATH: bf16 operands, source-swizzled global_load_lds,
// 3-buffer LDS rotation + counted vmcnt + raw s_barrier (no vmcnt(0) drain).
// ===========================================================================

// f32 -> bf16 conversion, 8 elems/thread/iter, grid-stride
__global__ __launch_bounds__(256) void k_cvt(
    const float* __restrict__ src, unsigned short* __restrict__ dst, int n8) {
  int i = blockIdx.x * blockDim.x + threadIdx.x;
  const int stride = gridDim.x * blockDim.x;
  for (; i < n8; i += stride) {
    const float4* s = (const float4*)(src + (size_t)i * 8);
    float4 a = s[0], b = s[1];
    *(ushort8*)(dst + (size_t)i * 8) = cvt8(a, b);
  }
}

// Core: 128x128 tile, BK=32, 4 waves (2x2), per-wave 64x64 (4x4 16x16x32 frags).
// LDS: 3 rotating 8KB buffers per operand (48 KB total) -> 3 blocks/CU.
// Pipeline: iteration t reads buf[t%3], issues tile t+2 into buf[(t+2)%3]
// (held tile t-1, reads completed before prior barrier -> provably race-free).
// End of iteration: s_waitcnt vmcnt(4) (tile t+1 landed, t+2 in flight) +
// raw s_barrier. Loads stay in flight across barriers (T3/T4).
template <int NTK>
__device__ __forceinline__ void gemm_core3(
    const unsigned short* __restrict__ Ag, const unsigned short* __restrict__ Bg,
    int ldk, unsigned short* As, unsigned short* Bs, f32x4 (&acc)[4][4]) {
  const int tid = threadIdx.x, lane = tid & 63, wv = tid >> 6;
  const int wr = wv >> 1, wc = wv & 1;
  const int l4 = lane >> 2, lc = lane & 3;
  // fetch-side pre-swizzle: content at linear DMA dest must equal the chunk the
  // swizzled ds_read expects there (same involution as lds_byte).
  const int kfetch = (lc * 8) ^ ((l4 & 6) << 2);  // bf16 units

  // stage K-tile t (both operands) into buffer m: 4 gload_lds(16B)/thread
#define STAGE_TILE(T, M)                                                     \
  {                                                                          \
    _Pragma("unroll") for (int s = 0; s < 2; ++s) {                          \
      const int row = s * 64 + wv * 16 + l4;                                 \
      const size_t go = (size_t)row * ldk + (size_t)(T) * 32 + kfetch;       \
      gload_lds16(Ag + go, As + (M) * 4096 + (s * 4 + wv) * 512);            \
      gload_lds16(Bg + go, Bs + (M) * 4096 + (s * 4 + wv) * 512);            \
    }                                                                        \
  }

  STAGE_TILE(0, 0);
  STAGE_TILE(1, 1);
  asm volatile("s_waitcnt vmcnt(4)" ::: "memory");  // tile 0 landed
  __builtin_amdgcn_s_barrier();

  int cur = 0;
  for (int t = 0; t < NTK; ++t) {
    const int nxt = (cur + 2 >= 3) ? cur - 1 : cur + 2;  // (cur+2)%3
    if (t + 2 < NTK) STAGE_TILE(t + 2, nxt);

    const char* Ab = (const char*)(As + cur * 4096);
    const char* Bb = (const char*)(Bs + cur * 4096);
    const int kb = (lane >> 4) * 16;
    short8 af[4], bfv[4];
#pragma unroll
    for (int m = 0; m < 4; ++m) {
      const int r = wr * 64 + m * 16 + (lane & 15);
      af[m] = *(const short8*)(Ab + lds_byte(r, kb));
    }
#pragma unroll
    for (int n = 0; n < 4; ++n) {
      const int r = wc * 64 + n * 16 + (lane & 15);
      bfv[n] = *(const short8*)(Bb + lds_byte(r, kb));
    }
#pragma unroll
    for (int m = 0; m < 4; ++m)
#pragma unroll
      for (int n = 0; n < 4; ++n)
        acc[m][n] = __builtin_amdgcn_mfma_f32_16x16x32_bf16(
            af[m], bfv[n], acc[m][n], 0, 0, 0);

    // counted wait: tile t+1 (oldest 4 loads) landed; t+2 stays in flight.
    if (t + 2 < NTK) {
      asm volatile("s_waitcnt vmcnt(4)" ::: "memory");
    } else {
      asm volatile("s_waitcnt vmcnt(0)" ::: "memory");
    }
    __builtin_amdgcn_s_barrier();
    cur = (cur + 1 == 3) ? 0 : cur + 1;
  }
#undef STAGE_TILE
}

// Stage 1 (bf16 in): eoT[b][o][e][c] = sum_i W[e,o,i]*x[b,e,c,i] + bias[o]
__global__ __launch_bounds__(256, 3) void k_gemm1f(
    const unsigned short* __restrict__ xb, const unsigned short* __restrict__ Wb,
    const float* __restrict__ bias, unsigned short* __restrict__ eoT) {
  const int tile = blockIdx.x;  // 32 o-tiles x 4 c-tiles
  const int e = blockIdx.y, b = blockIdx.z;
  const int bm = tile >> 2, bn = tile & 3;
  const int tid = threadIdx.x, lane = tid & 63, wv = tid >> 6;
  const int wr = wv >> 1, wc = wv & 1;

  const unsigned short* Ag = Wb + (size_t)e * NO * NI + (size_t)(bm * 128) * NI;
  const unsigned short* Bg = xb + ((size_t)b * NE + e) * NC * NI + (size_t)(bn * 128) * NI;

  __shared__ __align__(16) unsigned short As[3 * 128 * 32];
  __shared__ __align__(16) unsigned short Bs[3 * 128 * 32];

  f32x4 acc[4][4];
#pragma unroll
  for (int m = 0; m < 4; ++m)
#pragma unroll
    for (int n = 0; n < 4; ++n) acc[m][n] = (f32x4)0.f;

  gemm_core3<NI / 32>(Ag, Bg, NI, As, Bs, acc);

  const int o0 = bm * 128 + wr * 64;
  const int c0 = bn * 128 + wc * 64;
#pragma unroll
  for (int m = 0; m < 4; ++m) {
#pragma unroll
    for (int j = 0; j < 4; ++j) {
      const int o = o0 + m * 16 + (lane >> 4) * 4 + j;
      const float bv = bias[o];
      const size_t base = (((size_t)b * NO + o) * NE + e) * NC + c0;
#pragma unroll
      for (int n = 0; n < 4; ++n)
        eoT[base + n * 16 + (lane & 15)] = f2bf(acc[m][n][j] + bv);
    }
  }
}

// Stage 2 (bf16 in): out[b,t,o] = sum_{ec} comb[b,t,e,c] * eoT[b,o,e,c]
__global__ __launch_bounds__(256, 3) void k_gemm2f(
    const unsigned short* __restrict__ cb, const unsigned short* __restrict__ eoT,
    float* __restrict__ out) {
  const int b = blockIdx.y;
  const int bm = blockIdx.x >> 5;  // t-tile
  const int bn = blockIdx.x & 31;  // o-tile (fast -> A-panel L2 reuse)
  const int tid = threadIdx.x, lane = tid & 63, wv = tid >> 6;
  const int wr = wv >> 1, wc = wv & 1;

  const unsigned short* Ag = cb + (size_t)b * NT * NEC + (size_t)(bm * 128) * NEC;
  const unsigned short* Bg = eoT + (size_t)b * NO * NEC + (size_t)(bn * 128) * NEC;

  __shared__ __align__(16) unsigned short As[3 * 128 * 32];
  __shared__ __align__(16) unsigned short Bs[3 * 128 * 32];

  f32x4 acc[4][4];
#pragma unroll
  for (int m = 0; m < 4; ++m)
#pragma unroll
    for (int n = 0; n < 4; ++n) acc[m][n] = (f32x4)0.f;

  gemm_core3<NEC / 32>(Ag, Bg, NEC, As, Bs, acc);

  const int t0 = bm * 128 + wr * 64;
  const int o0 = bn * 128 + wc * 64;
#pragma unroll
  for (int m = 0; m < 4; ++m) {
#pragma unroll
    for (int j = 0; j < 4; ++j) {
      const int t = t0 + m * 16 + (lane >> 4) * 4 + j;
      float* op = out + ((size_t)b * NT + t) * NO + o0;
#pragma unroll
      for (int n = 0; n < 4; ++n) op[n * 16 + (lane & 15)] = acc[m][n][j];
    }
  }
}

// ===========================================================================
// FALLBACK PATH (round-4 verified kernels) — used when ws_size < 201 MB
// ===========================================================================

__global__ __launch_bounds__(256, 2) void k_gemm1(
    const float* __restrict__ x, const float* __restrict__ W,
    const float* __restrict__ bias, unsigned short* __restrict__ eoT) {
  const int tile = blockIdx.x;
  const int e = blockIdx.y, b = blockIdx.z;
  const int bm = tile >> 2, bn = tile & 3;
  const int tid = threadIdx.x, lane = tid & 63, wv = tid >> 6;
  const int wr = wv >> 1, wc = wv & 1;

  const float* Ag = W + (size_t)e * NO * NI + (size_t)(bm * 128) * NI;
  const float* Bg = x + ((size_t)b * NE + e) * NC * NI + (size_t)(bn * 128) * NI;

  __shared__ __align__(16) unsigned short As[128 * 32];
  __shared__ __align__(16) unsigned short Bs[128 * 32];

  f32x4 acc[4][4];
#pragma unroll
  for (int m = 0; m < 4; ++m)
#pragma unroll
    for (int n = 0; n < 4; ++n) acc[m][n] = (f32x4)0.f;

  for (int k0 = 0; k0 < NI; k0 += 32) {
    __syncthreads();
#pragma unroll
    for (int s = 0; s < 2; ++s) {
      const int q = tid + s * 256;
      const int row = q >> 2, kc = (q & 3) * 8;
      const float* ga = Ag + (size_t)row * NI + k0 + kc;
      float4 a0 = *(const float4*)ga;
      float4 a1 = *(const float4*)(ga + 4);
      *(ushort8*)((char*)As + lds_byte(row, kc * 2)) = cvt8(a0, a1);
      const float* gb = Bg + (size_t)row * NI + k0 + kc;
      float4 b0 = *(const float4*)gb;
      float4 b1 = *(const float4*)(gb + 4);
      *(ushort8*)((char*)Bs + lds_byte(row, kc * 2)) = cvt8(b0, b1);
    }
    __syncthreads();

    const int kb = (lane >> 4) * 16;
    short8 af[4], bfv[4];
#pragma unroll
    for (int m = 0; m < 4; ++m) {
      const int r = wr * 64 + m * 16 + (lane & 15);
      af[m] = *(const short8*)((const char*)As + lds_byte(r, kb));
    }
#pragma unroll
    for (int n = 0; n < 4; ++n) {
      const int r = wc * 64 + n * 16 + (lane & 15);
      bfv[n] = *(const short8*)((const char*)Bs + lds_byte(r, kb));
    }
#pragma unroll
    for (int m = 0; m < 4; ++m)
#pragma unroll
      for (int n = 0; n < 4; ++n)
        acc[m][n] = __builtin_amdgcn_mfma_f32_16x16x32_bf16(
            af[m], bfv[n], acc[m][n], 0, 0, 0);
  }

  const int o0 = bm * 128 + wr * 64;
  const int c0 = bn * 128 + wc * 64;
#pragma unroll
  for (int m = 0; m < 4; ++m) {
#pragma unroll
    for (int j = 0; j < 4; ++j) {
      const int o = o0 + m * 16 + (lane >> 4) * 4 + j;
      const float bv = bias[o];
      const size_t base = (((size_t)b * NO + o) * NE + e) * NC + c0;
#pragma unroll
      for (int n = 0; n < 4; ++n)
        eoT[base + n * 16 + (lane & 15)] = f2bf(acc[m][n][j] + bv);
    }
  }
}

__global__ __launch_bounds__(256, 2) void k_gemm2(
    const float* __restrict__ comb, const unsigned short* __restrict__ eoT,
    float* __restrict__ out) {
  const int b = blockIdx.y;
  const int bm = blockIdx.x >> 5;
  const int bn = blockIdx.x & 31;
  const int tid = threadIdx.x, lane = tid & 63, wv = tid >> 6;
  const int wr = wv >> 1, wc = wv & 1;

  const float* Ag = comb + (size_t)b * NT * NEC + (size_t)(bm * 128) * NEC;
  const unsigned short* Bg = eoT + (size_t)b * NO * NEC + (size_t)(bn * 128) * NEC;

  __shared__ __align__(16) unsigned short As[128 * 32];
  __shared__ __align__(16) unsigned short Bs[128 * 32];

  f32x4 acc[4][4];
#pragma unroll
  for (int m = 0; m < 4; ++m)
#pragma unroll
    for (int n = 0; n < 4; ++n) acc[m][n] = (f32x4)0.f;

  for (int k0 = 0; k0 < NEC; k0 += 32) {
    __syncthreads();
#pragma unroll
    for (int s = 0; s < 2; ++s) {
      const int q = tid + s * 256;
      const int row = q >> 2, kc = (q & 3) * 8;
      const float* ga = Ag + (size_t)row * NEC + k0 + kc;
      float4 a0 = *(const float4*)ga;
      float4 a1 = *(const float4*)(ga + 4);
      *(ushort8*)((char*)As + lds_byte(row, kc * 2)) = cvt8(a0, a1);
      ushort8 bv = *(const ushort8*)(Bg + (size_t)row * NEC + k0 + kc);
      *(ushort8*)((char*)Bs + lds_byte(row, kc * 2)) = bv;
    }
    __syncthreads();

    const int kb = (lane >> 4) * 16;
    short8 af[4], bfv[4];
#pragma unroll
    for (int m = 0; m < 4; ++m) {
      const int r = wr * 64 + m * 16 + (lane & 15);
      af[m] = *(const short8*)((const char*)As + lds_byte(r, kb));
    }
#pragma unroll
    for (int n = 0; n < 4; ++n) {
      const int r = wc * 64 + n * 16 + (lane & 15);
      bfv[n] = *(const short8*)((const char*)Bs + lds_byte(r, kb));
    }
#pragma unroll
    for (int m = 0; m < 4; ++m)
#pragma unroll
      for (int n = 0; n < 4; ++n)
        acc[m][n] = __builtin_amdgcn_mfma_f32_16x16x32_bf16(
            af[m], bfv[n], acc[m][n], 0, 0, 0);
  }

  const int t0 = bm * 128 + wr * 64;
  const int o0 = bn * 128 + wc * 64;
#pragma unroll
  for (int m = 0; m < 4; ++m) {
#pragma unroll
    for (int j = 0; j < 4; ++j) {
      const int t = t0 + m * 16 + (lane >> 4) * 4 + j;
      float* op = out + ((size_t)b * NT + t) * NO + o0;
#pragma unroll
      for (int n = 0; n < 4; ++n) op[n * 16 + (lane & 15)] = acc[m][n][j];
    }
  }
}

extern "C" void kernel_launch(void* const* d_in, const int* in_sizes, int n_in,
                              void* d_out, int out_size, void* d_ws, size_t ws_size,
                              hipStream_t stream) {
  const float* x    = (const float*)d_in[0];  // [B,E,C,I]
  const float* comb = (const float*)d_in[1];  // [B,T,E,C]
  const float* W    = (const float*)d_in[2];  // [E,O,I]
  const float* bias = (const float*)d_in[3];  // [O]
  float* out = (float*)d_out;                 // [B,T,O]

  const size_t EOT_ELEMS = (size_t)NB * NO * NE * NC;   // 67,108,864 (x2B = 134MB)
  const size_t X_ELEMS   = (size_t)NB * NE * NC * NI;   //  8,388,608
  const size_t W_ELEMS   = (size_t)NE * NO * NI;        // 16,777,216
  const size_t C_ELEMS   = (size_t)NB * NT * NE * NC;   // 33,554,432
  const size_t region2_elems = (C_ELEMS > X_ELEMS + W_ELEMS) ? C_ELEMS : (X_ELEMS + W_ELEMS);
  const size_t need = (EOT_ELEMS + region2_elems) * 2;  // bytes = 201,326,592

  unsigned short* eoT = (unsigned short*)d_ws;

  if (ws_size >= need) {
    // Fast path: convert to bf16, 3-buffer counted-vmcnt GEMMs.
    // region2 time-shared: {xb, Wb} for stage 1, then comb_bf16 for stage 2.
    unsigned short* reg2 = eoT + EOT_ELEMS;
    unsigned short* xb = reg2;
    unsigned short* Wb = reg2 + X_ELEMS;
    unsigned short* cb = reg2;

    k_cvt<<<2048, 256, 0, stream>>>(x, xb, (int)(X_ELEMS / 8));
    k_cvt<<<2048, 256, 0, stream>>>(W, Wb, (int)(W_ELEMS / 8));
    k_gemm1f<<<dim3(128, NE, NB), 256, 0, stream>>>(xb, Wb, bias, eoT);
    k_cvt<<<2048, 256, 0, stream>>>(comb, cb, (int)(C_ELEMS / 8));
    k_gemm2f<<<dim3(512, NB), 256, 0, stream>>>(cb, eoT, out);
  } else {
    // Fallback: round-4 verified reg-staged kernels (needs only eoT = 134MB)
    k_gemm1<<<dim3(128, NE, NB), 256, 0, stream>>>(x, W, bias, eoT);
    k_gemm2<<<dim3(512, NB), 256, 0, stream>>>(comb, eoT, out);
  }
}

// Round 8
// 431.790 us; speedup vs baseline: 1.2246x; 1.2246x over previous
//
#include <hip/hip_runtime.h>
#include <hip/hip_bf16.h>
#include <cstdint>

// Problem constants: B,T,E,C,I_E,O = 4,2048,8,512,512,4096
constexpr int NB = 4;
constexpr int NT = 2048;
constexpr int NE = 8;
constexpr int NC = 512;
constexpr int NI = 512;
constexpr int NO = 4096;
constexpr int NEC = NE * NC;  // 4096 (stage-2 K)

typedef __attribute__((ext_vector_type(8))) short short8;
typedef __attribute__((ext_vector_type(8))) unsigned short ushort8;
typedef __attribute__((ext_vector_type(4))) float f32x4;

__device__ __forceinline__ unsigned short f2bf(float f) {
  unsigned int u = __builtin_bit_cast(unsigned int, f);
  u += 0x7FFFu + ((u >> 16) & 1u);
  return (unsigned short)(u >> 16);
}

__device__ __forceinline__ ushort8 cvt8(float4 a, float4 b) {
  ushort8 v;
  v[0] = f2bf(a.x); v[1] = f2bf(a.y); v[2] = f2bf(a.z); v[3] = f2bf(a.w);
  v[4] = f2bf(b.x); v[5] = f2bf(b.y); v[6] = f2bf(b.z); v[7] = f2bf(b.w);
  return v;
}

// round-6 swizzle for the 128x32 (64B-row) tiles of the 2-phase core
__device__ __forceinline__ int lds_byte(int row, int kbyte) {
  return (row * 64 + kbyte) ^ ((row & 6) << 3);
}

__device__ __forceinline__ void gload_lds16(const void* g, void* lds) {
  __builtin_amdgcn_global_load_lds(
      (const __attribute__((address_space(1))) unsigned int*)g,
      (__attribute__((address_space(3))) unsigned int*)lds, 16, 0, 0);
}

// f32 -> bf16 conversion, 8 elems/thread/iter, grid-stride
__global__ __launch_bounds__(256) void k_cvt(
    const float* __restrict__ src, unsigned short* __restrict__ dst, int n8) {
  int i = blockIdx.x * blockDim.x + threadIdx.x;
  const int stride = gridDim.x * blockDim.x;
  for (; i < n8; i += stride) {
    const float4* s = (const float4*)(src + (size_t)i * 8);
    float4 a = s[0], b = s[1];
    *(ushort8*)(dst + (size_t)i * 8) = cvt8(a, b);
  }
}

// ===========================================================================
// Round-6 verified 2-phase core (used for stage 1)
// ===========================================================================
template <int KTOT>
__device__ __forceinline__ void gemm_core(
    const unsigned short* __restrict__ Ag, const unsigned short* __restrict__ Bg,
    int ldk, unsigned short* As, unsigned short* Bs, f32x4 (&acc)[4][4]) {
  const int tid = threadIdx.x, lane = tid & 63, wv = tid >> 6;
  const int wr = wv >> 1, wc = wv & 1;
  const int l4 = lane >> 2, lc = lane & 3;
  const int kfetch = (lc * 8) ^ ((l4 & 6) << 2);

  for (int k0 = 0; k0 < KTOT; k0 += 32) {
    __syncthreads();
#pragma unroll
    for (int c = 0; c < 2; ++c) {
      const int q = wv * 2 + c;
      const int row = q * 16 + l4;
      const size_t goff = (size_t)row * ldk + k0 + kfetch;
      gload_lds16(Ag + goff, As + q * 512);
      gload_lds16(Bg + goff, Bs + q * 512);
    }
    __syncthreads();

    const int kb = (lane >> 4) * 16;
    short8 af[4], bfv[4];
#pragma unroll
    for (int m = 0; m < 4; ++m) {
      const int r = wr * 64 + m * 16 + (lane & 15);
      af[m] = *(const short8*)((const char*)As + lds_byte(r, kb));
    }
#pragma unroll
    for (int n = 0; n < 4; ++n) {
      const int r = wc * 64 + n * 16 + (lane & 15);
      bfv[n] = *(const short8*)((const char*)Bs + lds_byte(r, kb));
    }
#pragma unroll
    for (int m = 0; m < 4; ++m)
#pragma unroll
      for (int n = 0; n < 4; ++n)
        acc[m][n] = __builtin_amdgcn_mfma_f32_16x16x32_bf16(
            af[m], bfv[n], acc[m][n], 0, 0, 0);
  }
}

// Stage 1: eoT[b][o][e][c] = sum_i W[e,o,i]*x[b,e,c,i] + bias[o]
__global__ __launch_bounds__(256, 2) void k_gemm1f(
    const unsigned short* __restrict__ xb, const unsigned short* __restrict__ Wb,
    const float* __restrict__ bias, unsigned short* __restrict__ eoT) {
  const int tile = blockIdx.x;
  const int e = blockIdx.y, b = blockIdx.z;
  const int bm = tile >> 2, bn = tile & 3;
  const int tid = threadIdx.x, lane = tid & 63, wv = tid >> 6;
  const int wr = wv >> 1, wc = wv & 1;

  const unsigned short* Ag = Wb + (size_t)e * NO * NI + (size_t)(bm * 128) * NI;
  const unsigned short* Bg = xb + ((size_t)b * NE + e) * NC * NI + (size_t)(bn * 128) * NI;

  __shared__ __align__(16) unsigned short As[128 * 32];
  __shared__ __align__(16) unsigned short Bs[128 * 32];

  f32x4 acc[4][4];
#pragma unroll
  for (int m = 0; m < 4; ++m)
#pragma unroll
    for (int n = 0; n < 4; ++n) acc[m][n] = (f32x4)0.f;

  gemm_core<NI>(Ag, Bg, NI, As, Bs, acc);

  const int o0 = bm * 128 + wr * 64;
  const int c0 = bn * 128 + wc * 64;
#pragma unroll
  for (int m = 0; m < 4; ++m) {
#pragma unroll
    for (int j = 0; j < 4; ++j) {
      const int o = o0 + m * 16 + (lane >> 4) * 4 + j;
      const float bv = bias[o];
      const size_t base = (((size_t)b * NO + o) * NE + e) * NC + c0;
#pragma unroll
      for (int n = 0; n < 4; ++n)
        eoT[base + n * 16 + (lane & 15)] = f2bf(acc[m][n][j] + bv);
    }
  }
}

// ===========================================================================
// Stage 2: 256x256 8-phase K-half-slot pipeline (T2+T3+T4+T5)
// out[b,t,o] = sum_{ec} comb[b,t,e,c] * eoT[b,o,e,c]
// LDS: per operand 2 dbuf x 2 K-half slots (256 rows x 32 bf16 = 16KB each).
// Each phase: ds-load frag subtile + stage 1 slot + barrier + lgkm + 16 MFMA
// + barrier. vmcnt(6) only at phases 4/8. Each stage targets a slot whose
// last reader finished before the previous phase's end barrier (race-free).
// ===========================================================================
constexpr int NKT2 = NEC / 64;  // 64 K-tiles

__global__ __launch_bounds__(512, 2) void k_gemm2p(
    const unsigned short* __restrict__ cb, const unsigned short* __restrict__ eoT,
    float* __restrict__ out) {
  // bijective XCD swizzle over 512 blocks (512 % 8 == 0)
  const int bid = (blockIdx.x & 7) * 64 + (blockIdx.x >> 3);
  const int b  = bid >> 7;         // 4 batches
  const int bm = (bid >> 4) & 7;   // 8 t-tiles of 256
  const int bn = bid & 15;         // 16 o-tiles of 256

  const int tid = threadIdx.x, lane = tid & 63, wv = tid >> 6;
  const int wr = wv >> 2, wc = wv & 3;   // 2M x 4N waves
  const int g16 = lane >> 4;             // frag K-quarter
  const int fr  = lane & 15;             // frag row
  const int pc  = (g16 ^ (fr & 3)) << 4; // physical-chunk xor (lane const)

  const unsigned short* Ag = cb  + (size_t)b * NT * NEC + (size_t)(bm * 256) * NEC;
  const unsigned short* Bg = eoT + (size_t)b * NO * NEC + (size_t)(bn * 256) * NEC;

  __shared__ __align__(16) unsigned short lds[65536];  // 128 KB

  // staging: slot = 1024 x 16B chunks; thread covers 2; dest linear.
  // content pre-swizzle: fetch global chunk c ^ (row&3)  (lane constant).
  const int scg = (lane & 3) ^ ((lane >> 2) & 3);
  const size_t srow0 = (size_t)(wv * 16 + (lane >> 2)) * NEC + scg * 8;
  const size_t srowstep = (size_t)128 * NEC;
  const int sdst0 = wv * 512;  // ushorts within slot

#define ASLOT(D, KH) ((D) * 16384 + (KH) * 8192)
#define BSLOT(D, KH) (32768 + (D) * 16384 + (KH) * 8192)
#define STG(PTR, SLOT, KT, KH)                                              \
  {                                                                         \
    const unsigned short* _g = (PTR) + srow0 + (size_t)(KT) * 64 + (KH) * 32; \
    gload_lds16(_g, lds + (SLOT) + sdst0);                                  \
    gload_lds16(_g + srowstep, lds + (SLOT) + 4096 + sdst0);                \
  }
#define RD8(SLOT, R) \
  (*(const short8*)((const char*)lds + (SLOT) * 2 + (R) * 64 + pc))

  f32x4 acc[8][4];
#pragma unroll
  for (int m = 0; m < 8; ++m)
#pragma unroll
    for (int n = 0; n < 4; ++n) acc[m][n] = (f32x4)0.f;

  short8 af[8], bf0, bf1;

#define LDA(D, KH)                                      \
  _Pragma("unroll") for (int m = 0; m < 8; ++m) {       \
    af[m] = RD8(ASLOT(D, KH), wr * 128 + m * 16 + fr);  \
  }
#define LDB(D, KH, NH)                                  \
  {                                                     \
    const int r0 = wc * 64 + (NH) * 32 + fr;            \
    bf0 = RD8(BSLOT(D, KH), r0);                        \
    bf1 = RD8(BSLOT(D, KH), r0 + 16);                   \
  }
#define MFMA16(NH)                                                   \
  __builtin_amdgcn_s_setprio(1);                                     \
  _Pragma("unroll") for (int m = 0; m < 8; ++m) {                    \
    acc[m][(NH) * 2 + 0] = __builtin_amdgcn_mfma_f32_16x16x32_bf16(  \
        af[m], bf0, acc[m][(NH) * 2 + 0], 0, 0, 0);                  \
    acc[m][(NH) * 2 + 1] = __builtin_amdgcn_mfma_f32_16x16x32_bf16(  \
        af[m], bf1, acc[m][(NH) * 2 + 1], 0, 0, 0);                  \
  }                                                                  \
  __builtin_amdgcn_s_setprio(0);
#define WAITK()                                        \
  asm volatile("s_waitcnt lgkmcnt(0)" ::: "memory");   \
  __builtin_amdgcn_sched_barrier(0);
#define BAR() __builtin_amdgcn_s_barrier()

  // prologue: KT0 {A0,B0,A1,B1} + KT1 {A0,B0,A1}  (14 loads)
  STG(Ag, ASLOT(0, 0), 0, 0); STG(Bg, BSLOT(0, 0), 0, 0);
  STG(Ag, ASLOT(0, 1), 0, 1); STG(Bg, BSLOT(0, 1), 0, 1);
  STG(Ag, ASLOT(1, 0), 1, 0); STG(Bg, BSLOT(1, 0), 1, 0);
  STG(Ag, ASLOT(1, 1), 1, 1);
  asm volatile("s_waitcnt vmcnt(6)" ::: "memory");  // KT0 landed
  BAR();

  for (int it = 0; it < NKT2 / 2; ++it) {
    const int k1 = 2 * it + 1;
    const int k2 = (2 * it + 2) & (NKT2 - 1);  // wrap: uniform counts, no tail
    const int k3 = (2 * it + 3) & (NKT2 - 1);
    // ph1: compute (nh0,kk0) dbuf0 ; stage dbuf1.B-kh1 <- KT(2it+1)
    LDA(0, 0); LDB(0, 0, 0);
    STG(Bg, BSLOT(1, 1), k1, 1);
    BAR(); WAITK(); MFMA16(0); BAR();
    // ph2: (nh1,kk0) ; stage dbuf0.A-kh0 <- KT(2it+2)
    LDB(0, 0, 1);
    STG(Ag, ASLOT(0, 0), k2, 0);
    BAR(); WAITK(); MFMA16(1); BAR();
    // ph3: (nh0,kk1) ; stage dbuf0.B-kh0
    LDA(0, 1); LDB(0, 1, 0);
    STG(Bg, BSLOT(0, 0), k2, 0);
    BAR(); WAITK(); MFMA16(0); BAR();
    // ph4: (nh1,kk1) ; stage dbuf0.A-kh1 ; vmcnt(6)
    LDB(0, 1, 1);
    STG(Ag, ASLOT(0, 1), k2, 1);
    asm volatile("s_waitcnt vmcnt(6)" ::: "memory");
    BAR(); WAITK(); MFMA16(1); BAR();
    // ph5: dbuf1 (nh0,kk0) ; stage dbuf0.B-kh1
    LDA(1, 0); LDB(1, 0, 0);
    STG(Bg, BSLOT(0, 1), k2, 1);
    BAR(); WAITK(); MFMA16(0); BAR();
    // ph6: (nh1,kk0) ; stage dbuf1.A-kh0 <- KT(2it+3)
    LDB(1, 0, 1);
    STG(Ag, ASLOT(1, 0), k3, 0);
    BAR(); WAITK(); MFMA16(1); BAR();
    // ph7: (nh0,kk1) ; stage dbuf1.B-kh0
    LDA(1, 1); LDB(1, 1, 0);
    STG(Bg, BSLOT(1, 0), k3, 0);
    BAR(); WAITK(); MFMA16(0); BAR();
    // ph8: (nh1,kk1) ; stage dbuf1.A-kh1 ; vmcnt(6)
    LDB(1, 1, 1);
    STG(Ag, ASLOT(1, 1), k3, 1);
    asm volatile("s_waitcnt vmcnt(6)" ::: "memory");
    BAR(); WAITK(); MFMA16(1); BAR();
  }
  asm volatile("s_waitcnt vmcnt(0)" ::: "memory");

  const int t0 = bm * 256 + wr * 128;
  const int o0 = bn * 256 + wc * 64;
#pragma unroll
  for (int m = 0; m < 8; ++m) {
#pragma unroll
    for (int j = 0; j < 4; ++j) {
      const int t = t0 + m * 16 + g16 * 4 + j;
      float* op = out + ((size_t)b * NT + t) * NO + o0;
#pragma unroll
      for (int n = 0; n < 4; ++n) op[n * 16 + fr] = acc[m][n][j];
    }
  }
#undef ASLOT
#undef BSLOT
#undef STG
#undef RD8
#undef LDA
#undef LDB
#undef MFMA16
#undef WAITK
#undef BAR
}

// ===========================================================================
// FALLBACK (round-4 verified) — used when ws_size < 201 MB
// ===========================================================================
__global__ __launch_bounds__(256, 2) void k_gemm1(
    const float* __restrict__ x, const float* __restrict__ W,
    const float* __restrict__ bias, unsigned short* __restrict__ eoT) {
  const int tile = blockIdx.x;
  const int e = blockIdx.y, b = blockIdx.z;
  const int bm = tile >> 2, bn = tile & 3;
  const int tid = threadIdx.x, lane = tid & 63, wv = tid >> 6;
  const int wr = wv >> 1, wc = wv & 1;

  const float* Ag = W + (size_t)e * NO * NI + (size_t)(bm * 128) * NI;
  const float* Bg = x + ((size_t)b * NE + e) * NC * NI + (size_t)(bn * 128) * NI;

  __shared__ __align__(16) unsigned short As[128 * 32];
  __shared__ __align__(16) unsigned short Bs[128 * 32];

  f32x4 acc[4][4];
#pragma unroll
  for (int m = 0; m < 4; ++m)
#pragma unroll
    for (int n = 0; n < 4; ++n) acc[m][n] = (f32x4)0.f;

  for (int k0 = 0; k0 < NI; k0 += 32) {
    __syncthreads();
#pragma unroll
    for (int s = 0; s < 2; ++s) {
      const int q = tid + s * 256;
      const int row = q >> 2, kc = (q & 3) * 8;
      const float* ga = Ag + (size_t)row * NI + k0 + kc;
      float4 a0 = *(const float4*)ga;
      float4 a1 = *(const float4*)(ga + 4);
      *(ushort8*)((char*)As + lds_byte(row, kc * 2)) = cvt8(a0, a1);
      const float* gb = Bg + (size_t)row * NI + k0 + kc;
      float4 b0 = *(const float4*)gb;
      float4 b1 = *(const float4*)(gb + 4);
      *(ushort8*)((char*)Bs + lds_byte(row, kc * 2)) = cvt8(b0, b1);
    }
    __syncthreads();

    const int kb = (lane >> 4) * 16;
    short8 af[4], bfv[4];
#pragma unroll
    for (int m = 0; m < 4; ++m) {
      const int r = wr * 64 + m * 16 + (lane & 15);
      af[m] = *(const short8*)((const char*)As + lds_byte(r, kb));
    }
#pragma unroll
    for (int n = 0; n < 4; ++n) {
      const int r = wc * 64 + n * 16 + (lane & 15);
      bfv[n] = *(const short8*)((const char*)Bs + lds_byte(r, kb));
    }
#pragma unroll
    for (int m = 0; m < 4; ++m)
#pragma unroll
      for (int n = 0; n < 4; ++n)
        acc[m][n] = __builtin_amdgcn_mfma_f32_16x16x32_bf16(
            af[m], bfv[n], acc[m][n], 0, 0, 0);
  }

  const int o0 = bm * 128 + wr * 64;
  const int c0 = bn * 128 + wc * 64;
#pragma unroll
  for (int m = 0; m < 4; ++m) {
#pragma unroll
    for (int j = 0; j < 4; ++j) {
      const int o = o0 + m * 16 + (lane >> 4) * 4 + j;
      const float bv = bias[o];
      const size_t base = (((size_t)b * NO + o) * NE + e) * NC + c0;
#pragma unroll
      for (int n = 0; n < 4; ++n)
        eoT[base + n * 16 + (lane & 15)] = f2bf(acc[m][n][j] + bv);
    }
  }
}

__global__ __launch_bounds__(256, 2) void k_gemm2(
    const float* __restrict__ comb, const unsigned short* __restrict__ eoT,
    float* __restrict__ out) {
  const int b = blockIdx.y;
  const int bm = blockIdx.x >> 5;
  const int bn = blockIdx.x & 31;
  const int tid = threadIdx.x, lane = tid & 63, wv = tid >> 6;
  const int wr = wv >> 1, wc = wv & 1;

  const float* Ag = comb + (size_t)b * NT * NEC + (size_t)(bm * 128) * NEC;
  const unsigned short* Bg = eoT + (size_t)b * NO * NEC + (size_t)(bn * 128) * NEC;

  __shared__ __align__(16) unsigned short As[128 * 32];
  __shared__ __align__(16) unsigned short Bs[128 * 32];

  f32x4 acc[4][4];
#pragma unroll
  for (int m = 0; m < 4; ++m)
#pragma unroll
    for (int n = 0; n < 4; ++n) acc[m][n] = (f32x4)0.f;

  for (int k0 = 0; k0 < NEC; k0 += 32) {
    __syncthreads();
#pragma unroll
    for (int s = 0; s < 2; ++s) {
      const int q = tid + s * 256;
      const int row = q >> 2, kc = (q & 3) * 8;
      const float* ga = Ag + (size_t)row * NEC + k0 + kc;
      float4 a0 = *(const float4*)ga;
      float4 a1 = *(const float4*)(ga + 4);
      *(ushort8*)((char*)As + lds_byte(row, kc * 2)) = cvt8(a0, a1);
      ushort8 bv = *(const ushort8*)(Bg + (size_t)row * NEC + k0 + kc);
      *(ushort8*)((char*)Bs + lds_byte(row, kc * 2)) = bv;
    }
    __syncthreads();

    const int kb = (lane >> 4) * 16;
    short8 af[4], bfv[4];
#pragma unroll
    for (int m = 0; m < 4; ++m) {
      const int r = wr * 64 + m * 16 + (lane & 15);
      af[m] = *(const short8*)((const char*)As + lds_byte(r, kb));
    }
#pragma unroll
    for (int n = 0; n < 4; ++n) {
      const int r = wc * 64 + n * 16 + (lane & 15);
      bfv[n] = *(const short8*)((const char*)Bs + lds_byte(r, kb));
    }
#pragma unroll
    for (int m = 0; m < 4; ++m)
#pragma unroll
      for (int n = 0; n < 4; ++n)
        acc[m][n] = __builtin_amdgcn_mfma_f32_16x16x32_bf16(
            af[m], bfv[n], acc[m][n], 0, 0, 0);
  }

  const int t0 = bm * 128 + wr * 64;
  const int o0 = bn * 128 + wc * 64;
#pragma unroll
  for (int m = 0; m < 4; ++m) {
#pragma unroll
    for (int j = 0; j < 4; ++j) {
      const int t = t0 + m * 16 + (lane >> 4) * 4 + j;
      float* op = out + ((size_t)b * NT + t) * NO + o0;
#pragma unroll
      for (int n = 0; n < 4; ++n) op[n * 16 + (lane & 15)] = acc[m][n][j];
    }
  }
}

extern "C" void kernel_launch(void* const* d_in, const int* in_sizes, int n_in,
                              void* d_out, int out_size, void* d_ws, size_t ws_size,
                              hipStream_t stream) {
  const float* x    = (const float*)d_in[0];  // [B,E,C,I]
  const float* comb = (const float*)d_in[1];  // [B,T,E,C]
  const float* W    = (const float*)d_in[2];  // [E,O,I]
  const float* bias = (const float*)d_in[3];  // [O]
  float* out = (float*)d_out;                 // [B,T,O]

  const size_t EOT_ELEMS = (size_t)NB * NO * NE * NC;   // 67,108,864
  const size_t X_ELEMS   = (size_t)NB * NE * NC * NI;   //  8,388,608
  const size_t W_ELEMS   = (size_t)NE * NO * NI;        // 16,777,216
  const size_t C_ELEMS   = (size_t)NB * NT * NE * NC;   // 33,554,432
  const size_t region2_elems = (C_ELEMS > X_ELEMS + W_ELEMS) ? C_ELEMS : (X_ELEMS + W_ELEMS);
  const size_t need = (EOT_ELEMS + region2_elems) * 2;  // 201,326,592 B

  unsigned short* eoT = (unsigned short*)d_ws;

  if (ws_size >= need) {
    unsigned short* reg2 = eoT + EOT_ELEMS;
    unsigned short* xb = reg2;
    unsigned short* Wb = reg2 + X_ELEMS;
    unsigned short* cbp = reg2;

    k_cvt<<<2048, 256, 0, stream>>>(x, xb, (int)(X_ELEMS / 8));
    k_cvt<<<2048, 256, 0, stream>>>(W, Wb, (int)(W_ELEMS / 8));
    k_gemm1f<<<dim3(128, NE, NB), 256, 0, stream>>>(xb, Wb, bias, eoT);
    k_cvt<<<2048, 256, 0, stream>>>(comb, cbp, (int)(C_ELEMS / 8));
    k_gemm2p<<<512, 512, 0, stream>>>(cbp, eoT, out);
  } else {
    k_gemm1<<<dim3(128, NE, NB), 256, 0, stream>>>(x, W, bias, eoT);
    k_gemm2<<<dim3(512, NB), 256, 0, stream>>>(comb, eoT, out);
  }
}

// Round 9
// 414.703 us; speedup vs baseline: 1.2751x; 1.0412x over previous
//
#include <hip/hip_runtime.h>
#include <hip/hip_bf16.h>
#include <cstdint>

// Problem constants: B,T,E,C,I_E,O = 4,2048,8,512,512,4096
constexpr int NB = 4;
constexpr int NT = 2048;
constexpr int NE = 8;
constexpr int NC = 512;
constexpr int NI = 512;
constexpr int NO = 4096;
constexpr int NEC = NE * NC;  // 4096 (stage-2 K)

typedef __attribute__((ext_vector_type(8))) short short8;
typedef __attribute__((ext_vector_type(8))) unsigned short ushort8;
typedef __attribute__((ext_vector_type(4))) float f32x4;

__device__ __forceinline__ unsigned short f2bf(float f) {
  unsigned int u = __builtin_bit_cast(unsigned int, f);
  u += 0x7FFFu + ((u >> 16) & 1u);
  return (unsigned short)(u >> 16);
}

__device__ __forceinline__ ushort8 cvt8(float4 a, float4 b) {
  ushort8 v;
  v[0] = f2bf(a.x); v[1] = f2bf(a.y); v[2] = f2bf(a.z); v[3] = f2bf(a.w);
  v[4] = f2bf(b.x); v[5] = f2bf(b.y); v[6] = f2bf(b.z); v[7] = f2bf(b.w);
  return v;
}

// round-6 swizzle for the 128x32 (64B-row) tiles of the 2-phase core
__device__ __forceinline__ int lds_byte(int row, int kbyte) {
  return (row * 64 + kbyte) ^ ((row & 6) << 3);
}

__device__ __forceinline__ void gload_lds16(const void* g, void* lds) {
  __builtin_amdgcn_global_load_lds(
      (const __attribute__((address_space(1))) unsigned int*)g,
      (__attribute__((address_space(3))) unsigned int*)lds, 16, 0, 0);
}

// f32 -> bf16 conversion, 8 elems/thread/iter, grid-stride
__global__ __launch_bounds__(256) void k_cvt(
    const float* __restrict__ src, unsigned short* __restrict__ dst, int n8) {
  int i = blockIdx.x * blockDim.x + threadIdx.x;
  const int stride = gridDim.x * blockDim.x;
  for (; i < n8; i += stride) {
    const float4* s = (const float4*)(src + (size_t)i * 8);
    float4 a = s[0], b = s[1];
    *(ushort8*)(dst + (size_t)i * 8) = cvt8(a, b);
  }
}

// ===========================================================================
// Round-6 verified 2-phase core (used for stage 1)
// ===========================================================================
template <int KTOT>
__device__ __forceinline__ void gemm_core(
    const unsigned short* __restrict__ Ag, const unsigned short* __restrict__ Bg,
    int ldk, unsigned short* As, unsigned short* Bs, f32x4 (&acc)[4][4]) {
  const int tid = threadIdx.x, lane = tid & 63, wv = tid >> 6;
  const int wr = wv >> 1, wc = wv & 1;
  const int l4 = lane >> 2, lc = lane & 3;
  const int kfetch = (lc * 8) ^ ((l4 & 6) << 2);

  for (int k0 = 0; k0 < KTOT; k0 += 32) {
    __syncthreads();
#pragma unroll
    for (int c = 0; c < 2; ++c) {
      const int q = wv * 2 + c;
      const int row = q * 16 + l4;
      const size_t goff = (size_t)row * ldk + k0 + kfetch;
      gload_lds16(Ag + goff, As + q * 512);
      gload_lds16(Bg + goff, Bs + q * 512);
    }
    __syncthreads();

    const int kb = (lane >> 4) * 16;
    short8 af[4], bfv[4];
#pragma unroll
    for (int m = 0; m < 4; ++m) {
      const int r = wr * 64 + m * 16 + (lane & 15);
      af[m] = *(const short8*)((const char*)As + lds_byte(r, kb));
    }
#pragma unroll
    for (int n = 0; n < 4; ++n) {
      const int r = wc * 64 + n * 16 + (lane & 15);
      bfv[n] = *(const short8*)((const char*)Bs + lds_byte(r, kb));
    }
#pragma unroll
    for (int m = 0; m < 4; ++m)
#pragma unroll
      for (int n = 0; n < 4; ++n)
        acc[m][n] = __builtin_amdgcn_mfma_f32_16x16x32_bf16(
            af[m], bfv[n], acc[m][n], 0, 0, 0);
  }
}

// Stage 1: eoT[b][o][e][c] = sum_i W[e,o,i]*x[b,e,c,i] + bias[o]
__global__ __launch_bounds__(256, 2) void k_gemm1f(
    const unsigned short* __restrict__ xb, const unsigned short* __restrict__ Wb,
    const float* __restrict__ bias, unsigned short* __restrict__ eoT) {
  const int tile = blockIdx.x;
  const int e = blockIdx.y, b = blockIdx.z;
  const int bm = tile >> 2, bn = tile & 3;
  const int tid = threadIdx.x, lane = tid & 63, wv = tid >> 6;
  const int wr = wv >> 1, wc = wv & 1;

  const unsigned short* Ag = Wb + (size_t)e * NO * NI + (size_t)(bm * 128) * NI;
  const unsigned short* Bg = xb + ((size_t)b * NE + e) * NC * NI + (size_t)(bn * 128) * NI;

  __shared__ __align__(16) unsigned short As[128 * 32];
  __shared__ __align__(16) unsigned short Bs[128 * 32];

  f32x4 acc[4][4];
#pragma unroll
  for (int m = 0; m < 4; ++m)
#pragma unroll
    for (int n = 0; n < 4; ++n) acc[m][n] = (f32x4)0.f;

  gemm_core<NI>(Ag, Bg, NI, As, Bs, acc);

  const int o0 = bm * 128 + wr * 64;
  const int c0 = bn * 128 + wc * 64;
#pragma unroll
  for (int m = 0; m < 4; ++m) {
#pragma unroll
    for (int j = 0; j < 4; ++j) {
      const int o = o0 + m * 16 + (lane >> 4) * 4 + j;
      const float bv = bias[o];
      const size_t base = (((size_t)b * NO + o) * NE + e) * NC + c0;
#pragma unroll
      for (int n = 0; n < 4; ++n)
        eoT[base + n * 16 + (lane & 15)] = f2bf(acc[m][n][j] + bv);
    }
  }
}

// ===========================================================================
// Stage 2: 256x256 8-phase K-half-slot pipeline (T2+T3+T4+T5)
// out[b,t,o] = sum_{ec} comb[b,t,e,c] * eoT[b,o,e,c]
// Swizzle (derived, 2-way=free): bank = 16*(R&1) + 4*chunk + sub;
// read chunk = g16 ^ ((fr>>1)&3) so (R&1,chunk) covers all 8 combos twice
// per 16-lane group. Store side applies the same involution via the
// pre-swizzled global source chunk (lane&3)^((lane>>3)&3).
// ===========================================================================
constexpr int NKT2 = NEC / 64;  // 64 K-tiles

__global__ __launch_bounds__(512, 2) void k_gemm2p(
    const unsigned short* __restrict__ cb, const unsigned short* __restrict__ eoT,
    float* __restrict__ out) {
  // bijective XCD swizzle over 512 blocks (512 % 8 == 0)
  const int bid = (blockIdx.x & 7) * 64 + (blockIdx.x >> 3);
  const int b  = bid >> 7;         // 4 batches
  const int bm = (bid >> 4) & 7;   // 8 t-tiles of 256
  const int bn = bid & 15;         // 16 o-tiles of 256

  const int tid = threadIdx.x, lane = tid & 63, wv = tid >> 6;
  const int wr = wv >> 2, wc = wv & 3;   // 2M x 4N waves
  const int g16 = lane >> 4;             // frag K-quarter
  const int fr  = lane & 15;             // frag row
  const int pc  = (g16 ^ ((fr >> 1) & 3)) << 4;  // physical-chunk byte offset

  const unsigned short* Ag = cb  + (size_t)b * NT * NEC + (size_t)(bm * 256) * NEC;
  const unsigned short* Bg = eoT + (size_t)b * NO * NEC + (size_t)(bn * 256) * NEC;

  __shared__ __align__(16) unsigned short lds[65536];  // 128 KB

  // staging: slot = 1024 x 16B chunks; thread covers 2; dest linear.
  // content pre-swizzle: fetch global chunk (lane&3) ^ ((row>>1)&3),
  // row = lane>>2  ->  scg = (lane&3) ^ ((lane>>3)&3).
  const int scg = (lane & 3) ^ ((lane >> 3) & 3);
  const size_t srow0 = (size_t)(wv * 16 + (lane >> 2)) * NEC + scg * 8;
  const size_t srowstep = (size_t)128 * NEC;
  const int sdst0 = wv * 512;  // ushorts within slot

#define ASLOT(D, KH) ((D) * 16384 + (KH) * 8192)
#define BSLOT(D, KH) (32768 + (D) * 16384 + (KH) * 8192)
#define STG(PTR, SLOT, KT, KH)                                              \
  {                                                                         \
    const unsigned short* _g = (PTR) + srow0 + (size_t)(KT) * 64 + (KH) * 32; \
    gload_lds16(_g, lds + (SLOT) + sdst0);                                  \
    gload_lds16(_g + srowstep, lds + (SLOT) + 4096 + sdst0);                \
  }
#define RD8(SLOT, R) \
  (*(const short8*)((const char*)lds + (SLOT) * 2 + (R) * 64 + pc))

  f32x4 acc[8][4];
#pragma unroll
  for (int m = 0; m < 8; ++m)
#pragma unroll
    for (int n = 0; n < 4; ++n) acc[m][n] = (f32x4)0.f;

  short8 af[8], bf0, bf1;

#define LDA(D, KH)                                      \
  _Pragma("unroll") for (int m = 0; m < 8; ++m) {       \
    af[m] = RD8(ASLOT(D, KH), wr * 128 + m * 16 + fr);  \
  }
#define LDB(D, KH, NH)                                  \
  {                                                     \
    const int r0 = wc * 64 + (NH) * 32 + fr;            \
    bf0 = RD8(BSLOT(D, KH), r0);                        \
    bf1 = RD8(BSLOT(D, KH), r0 + 16);                   \
  }
#define MFMA16(NH)                                                   \
  __builtin_amdgcn_s_setprio(1);                                     \
  _Pragma("unroll") for (int m = 0; m < 8; ++m) {                    \
    acc[m][(NH) * 2 + 0] = __builtin_amdgcn_mfma_f32_16x16x32_bf16(  \
        af[m], bf0, acc[m][(NH) * 2 + 0], 0, 0, 0);                  \
    acc[m][(NH) * 2 + 1] = __builtin_amdgcn_mfma_f32_16x16x32_bf16(  \
        af[m], bf1, acc[m][(NH) * 2 + 1], 0, 0, 0);                  \
  }                                                                  \
  __builtin_amdgcn_s_setprio(0);
#define WAITK()                                        \
  asm volatile("s_waitcnt lgkmcnt(0)" ::: "memory");   \
  __builtin_amdgcn_sched_barrier(0);
#define BAR() __builtin_amdgcn_s_barrier()

  // prologue: KT0 {A0,B0,A1,B1} + KT1 {A0,B0,A1}  (14 loads)
  STG(Ag, ASLOT(0, 0), 0, 0); STG(Bg, BSLOT(0, 0), 0, 0);
  STG(Ag, ASLOT(0, 1), 0, 1); STG(Bg, BSLOT(0, 1), 0, 1);
  STG(Ag, ASLOT(1, 0), 1, 0); STG(Bg, BSLOT(1, 0), 1, 0);
  STG(Ag, ASLOT(1, 1), 1, 1);
  asm volatile("s_waitcnt vmcnt(6)" ::: "memory");  // KT0 landed
  BAR();

  for (int it = 0; it < NKT2 / 2; ++it) {
    const int k1 = 2 * it + 1;
    const int k2 = (2 * it + 2) & (NKT2 - 1);  // wrap: uniform counts, no tail
    const int k3 = (2 * it + 3) & (NKT2 - 1);
    // ph1: compute (nh0,kk0) dbuf0 ; stage dbuf1.B-kh1 <- KT(2it+1)
    LDA(0, 0); LDB(0, 0, 0);
    STG(Bg, BSLOT(1, 1), k1, 1);
    BAR(); WAITK(); MFMA16(0); BAR();
    // ph2: (nh1,kk0) ; stage dbuf0.A-kh0 <- KT(2it+2)
    LDB(0, 0, 1);
    STG(Ag, ASLOT(0, 0), k2, 0);
    BAR(); WAITK(); MFMA16(1); BAR();
    // ph3: (nh0,kk1) ; stage dbuf0.B-kh0
    LDA(0, 1); LDB(0, 1, 0);
    STG(Bg, BSLOT(0, 0), k2, 0);
    BAR(); WAITK(); MFMA16(0); BAR();
    // ph4: (nh1,kk1) ; stage dbuf0.A-kh1 ; vmcnt(6)
    LDB(0, 1, 1);
    STG(Ag, ASLOT(0, 1), k2, 1);
    asm volatile("s_waitcnt vmcnt(6)" ::: "memory");
    BAR(); WAITK(); MFMA16(1); BAR();
    // ph5: dbuf1 (nh0,kk0) ; stage dbuf0.B-kh1
    LDA(1, 0); LDB(1, 0, 0);
    STG(Bg, BSLOT(0, 1), k2, 1);
    BAR(); WAITK(); MFMA16(0); BAR();
    // ph6: (nh1,kk0) ; stage dbuf1.A-kh0 <- KT(2it+3)
    LDB(1, 0, 1);
    STG(Ag, ASLOT(1, 0), k3, 0);
    BAR(); WAITK(); MFMA16(1); BAR();
    // ph7: (nh0,kk1) ; stage dbuf1.B-kh0
    LDA(1, 1); LDB(1, 1, 0);
    STG(Bg, BSLOT(1, 0), k3, 0);
    BAR(); WAITK(); MFMA16(0); BAR();
    // ph8: (nh1,kk1) ; stage dbuf1.A-kh1 ; vmcnt(6)
    LDB(1, 1, 1);
    STG(Ag, ASLOT(1, 1), k3, 1);
    asm volatile("s_waitcnt vmcnt(6)" ::: "memory");
    BAR(); WAITK(); MFMA16(1); BAR();
  }
  asm volatile("s_waitcnt vmcnt(0)" ::: "memory");

  const int t0 = bm * 256 + wr * 128;
  const int o0 = bn * 256 + wc * 64;
#pragma unroll
  for (int m = 0; m < 8; ++m) {
#pragma unroll
    for (int j = 0; j < 4; ++j) {
      const int t = t0 + m * 16 + g16 * 4 + j;
      float* op = out + ((size_t)b * NT + t) * NO + o0;
#pragma unroll
      for (int n = 0; n < 4; ++n) op[n * 16 + fr] = acc[m][n][j];
    }
  }
#undef ASLOT
#undef BSLOT
#undef STG
#undef RD8
#undef LDA
#undef LDB
#undef MFMA16
#undef WAITK
#undef BAR
}

// ===========================================================================
// FALLBACK (round-4 verified) — used when ws_size < 201 MB
// ===========================================================================
__global__ __launch_bounds__(256, 2) void k_gemm1(
    const float* __restrict__ x, const float* __restrict__ W,
    const float* __restrict__ bias, unsigned short* __restrict__ eoT) {
  const int tile = blockIdx.x;
  const int e = blockIdx.y, b = blockIdx.z;
  const int bm = tile >> 2, bn = tile & 3;
  const int tid = threadIdx.x, lane = tid & 63, wv = tid >> 6;
  const int wr = wv >> 1, wc = wv & 1;

  const float* Ag = W + (size_t)e * NO * NI + (size_t)(bm * 128) * NI;
  const float* Bg = x + ((size_t)b * NE + e) * NC * NI + (size_t)(bn * 128) * NI;

  __shared__ __align__(16) unsigned short As[128 * 32];
  __shared__ __align__(16) unsigned short Bs[128 * 32];

  f32x4 acc[4][4];
#pragma unroll
  for (int m = 0; m < 4; ++m)
#pragma unroll
    for (int n = 0; n < 4; ++n) acc[m][n] = (f32x4)0.f;

  for (int k0 = 0; k0 < NI; k0 += 32) {
    __syncthreads();
#pragma unroll
    for (int s = 0; s < 2; ++s) {
      const int q = tid + s * 256;
      const int row = q >> 2, kc = (q & 3) * 8;
      const float* ga = Ag + (size_t)row * NI + k0 + kc;
      float4 a0 = *(const float4*)ga;
      float4 a1 = *(const float4*)(ga + 4);
      *(ushort8*)((char*)As + lds_byte(row, kc * 2)) = cvt8(a0, a1);
      const float* gb = Bg + (size_t)row * NI + k0 + kc;
      float4 b0 = *(const float4*)gb;
      float4 b1 = *(const float4*)(gb + 4);
      *(ushort8*)((char*)Bs + lds_byte(row, kc * 2)) = cvt8(b0, b1);
    }
    __syncthreads();

    const int kb = (lane >> 4) * 16;
    short8 af[4], bfv[4];
#pragma unroll
    for (int m = 0; m < 4; ++m) {
      const int r = wr * 64 + m * 16 + (lane & 15);
      af[m] = *(const short8*)((const char*)As + lds_byte(r, kb));
    }
#pragma unroll
    for (int n = 0; n < 4; ++n) {
      const int r = wc * 64 + n * 16 + (lane & 15);
      bfv[n] = *(const short8*)((const char*)Bs + lds_byte(r, kb));
    }
#pragma unroll
    for (int m = 0; m < 4; ++m)
#pragma unroll
      for (int n = 0; n < 4; ++n)
        acc[m][n] = __builtin_amdgcn_mfma_f32_16x16x32_bf16(
            af[m], bfv[n], acc[m][n], 0, 0, 0);
  }

  const int o0 = bm * 128 + wr * 64;
  const int c0 = bn * 128 + wc * 64;
#pragma unroll
  for (int m = 0; m < 4; ++m) {
#pragma unroll
    for (int j = 0; j < 4; ++j) {
      const int o = o0 + m * 16 + (lane >> 4) * 4 + j;
      const float bv = bias[o];
      const size_t base = (((size_t)b * NO + o) * NE + e) * NC + c0;
#pragma unroll
      for (int n = 0; n < 4; ++n)
        eoT[base + n * 16 + (lane & 15)] = f2bf(acc[m][n][j] + bv);
    }
  }
}

__global__ __launch_bounds__(256, 2) void k_gemm2(
    const float* __restrict__ comb, const unsigned short* __restrict__ eoT,
    float* __restrict__ out) {
  const int b = blockIdx.y;
  const int bm = blockIdx.x >> 5;
  const int bn = blockIdx.x & 31;
  const int tid = threadIdx.x, lane = tid & 63, wv = tid >> 6;
  const int wr = wv >> 1, wc = wv & 1;

  const float* Ag = comb + (size_t)b * NT * NEC + (size_t)(bm * 128) * NEC;
  const unsigned short* Bg = eoT + (size_t)b * NO * NEC + (size_t)(bn * 128) * NEC;

  __shared__ __align__(16) unsigned short As[128 * 32];
  __shared__ __align__(16) unsigned short Bs[128 * 32];

  f32x4 acc[4][4];
#pragma unroll
  for (int m = 0; m < 4; ++m)
#pragma unroll
    for (int n = 0; n < 4; ++n) acc[m][n] = (f32x4)0.f;

  for (int k0 = 0; k0 < NEC; k0 += 32) {
    __syncthreads();
#pragma unroll
    for (int s = 0; s < 2; ++s) {
      const int q = tid + s * 256;
      const int row = q >> 2, kc = (q & 3) * 8;
      const float* ga = Ag + (size_t)row * NEC + k0 + kc;
      float4 a0 = *(const float4*)ga;
      float4 a1 = *(const float4*)(ga + 4);
      *(ushort8*)((char*)As + lds_byte(row, kc * 2)) = cvt8(a0, a1);
      ushort8 bv = *(const ushort8*)(Bg + (size_t)row * NEC + k0 + kc);
      *(ushort8*)((char*)Bs + lds_byte(row, kc * 2)) = bv;
    }
    __syncthreads();

    const int kb = (lane >> 4) * 16;
    short8 af[4], bfv[4];
#pragma unroll
    for (int m = 0; m < 4; ++m) {
      const int r = wr * 64 + m * 16 + (lane & 15);
      af[m] = *(const short8*)((const char*)As + lds_byte(r, kb));
    }
#pragma unroll
    for (int n = 0; n < 4; ++n) {
      const int r = wc * 64 + n * 16 + (lane & 15);
      bfv[n] = *(const short8*)((const char*)Bs + lds_byte(r, kb));
    }
#pragma unroll
    for (int m = 0; m < 4; ++m)
#pragma unroll
      for (int n = 0; n < 4; ++n)
        acc[m][n] = __builtin_amdgcn_mfma_f32_16x16x32_bf16(
            af[m], bfv[n], acc[m][n], 0, 0, 0);
  }

  const int t0 = bm * 128 + wr * 64;
  const int o0 = bn * 128 + wc * 64;
#pragma unroll
  for (int m = 0; m < 4; ++m) {
#pragma unroll
    for (int j = 0; j < 4; ++j) {
      const int t = t0 + m * 16 + (lane >> 4) * 4 + j;
      float* op = out + ((size_t)b * NT + t) * NO + o0;
#pragma unroll
      for (int n = 0; n < 4; ++n) op[n * 16 + (lane & 15)] = acc[m][n][j];
    }
  }
}

extern "C" void kernel_launch(void* const* d_in, const int* in_sizes, int n_in,
                              void* d_out, int out_size, void* d_ws, size_t ws_size,
                              hipStream_t stream) {
  const float* x    = (const float*)d_in[0];  // [B,E,C,I]
  const float* comb = (const float*)d_in[1];  // [B,T,E,C]
  const float* W    = (const float*)d_in[2];  // [E,O,I]
  const float* bias = (const float*)d_in[3];  // [O]
  float* out = (float*)d_out;                 // [B,T,O]

  const size_t EOT_ELEMS = (size_t)NB * NO * NE * NC;   // 67,108,864
  const size_t X_ELEMS   = (size_t)NB * NE * NC * NI;   //  8,388,608
  const size_t W_ELEMS   = (size_t)NE * NO * NI;        // 16,777,216
  const size_t C_ELEMS   = (size_t)NB * NT * NE * NC;   // 33,554,432
  const size_t region2_elems = (C_ELEMS > X_ELEMS + W_ELEMS) ? C_ELEMS : (X_ELEMS + W_ELEMS);
  const size_t need = (EOT_ELEMS + region2_elems) * 2;  // 201,326,592 B

  unsigned short* eoT = (unsigned short*)d_ws;

  if (ws_size >= need) {
    unsigned short* reg2 = eoT + EOT_ELEMS;
    unsigned short* xb = reg2;
    unsigned short* Wb = reg2 + X_ELEMS;
    unsigned short* cbp = reg2;

    k_cvt<<<2048, 256, 0, stream>>>(x, xb, (int)(X_ELEMS / 8));
    k_cvt<<<2048, 256, 0, stream>>>(W, Wb, (int)(W_ELEMS / 8));
    k_gemm1f<<<dim3(128, NE, NB), 256, 0, stream>>>(xb, Wb, bias, eoT);
    k_cvt<<<2048, 256, 0, stream>>>(comb, cbp, (int)(C_ELEMS / 8));
    k_gemm2p<<<512, 512, 0, stream>>>(cbp, eoT, out);
  } else {
    k_gemm1<<<dim3(128, NE, NB), 256, 0, stream>>>(x, W, bias, eoT);
    k_gemm2<<<dim3(512, NB), 256, 0, stream>>>(comb, eoT, out);
  }
}

// Round 10
// 403.713 us; speedup vs baseline: 1.3098x; 1.0272x over previous
//
#include <hip/hip_runtime.h>
#include <hip/hip_bf16.h>
#include <cstdint>

// Problem constants: B,T,E,C,I_E,O = 4,2048,8,512,512,4096
constexpr int NB = 4;
constexpr int NT = 2048;
constexpr int NE = 8;
constexpr int NC = 512;
constexpr int NI = 512;
constexpr int NO = 4096;
constexpr int NEC = NE * NC;  // 4096 (stage-2 K)

typedef __attribute__((ext_vector_type(8))) short short8;
typedef __attribute__((ext_vector_type(8))) unsigned short ushort8;
typedef __attribute__((ext_vector_type(4))) float f32x4;

__device__ __forceinline__ unsigned short f2bf(float f) {
  unsigned int u = __builtin_bit_cast(unsigned int, f);
  u += 0x7FFFu + ((u >> 16) & 1u);
  return (unsigned short)(u >> 16);
}

__device__ __forceinline__ ushort8 cvt8(float4 a, float4 b) {
  ushort8 v;
  v[0] = f2bf(a.x); v[1] = f2bf(a.y); v[2] = f2bf(a.z); v[3] = f2bf(a.w);
  v[4] = f2bf(b.x); v[5] = f2bf(b.y); v[6] = f2bf(b.z); v[7] = f2bf(b.w);
  return v;
}

// swizzle for the fallback 128x32 tiles
__device__ __forceinline__ int lds_byte(int row, int kbyte) {
  return (row * 64 + kbyte) ^ ((row & 6) << 3);
}

__device__ __forceinline__ void gload_lds16(const void* g, void* lds) {
  __builtin_amdgcn_global_load_lds(
      (const __attribute__((address_space(1))) unsigned int*)g,
      (__attribute__((address_space(3))) unsigned int*)lds, 16, 0, 0);
}

// f32 -> bf16 conversion, 8 elems/thread/iter, grid-stride
__global__ __launch_bounds__(256) void k_cvt(
    const float* __restrict__ src, unsigned short* __restrict__ dst, int n8) {
  int i = blockIdx.x * blockDim.x + threadIdx.x;
  const int stride = gridDim.x * blockDim.x;
  for (; i < n8; i += stride) {
    const float4* s = (const float4*)(src + (size_t)i * 8);
    float4 a = s[0], b = s[1];
    *(ushort8*)(dst + (size_t)i * 8) = cvt8(a, b);
  }
}

// ===========================================================================
// Shared 256x256 8-phase QUADRANT core (balanced 8/4 ds_reads per phase).
// 8 waves (2M x 4N), per-wave 128x64, BK=64 as 2 K-half slots per dbuf.
// Phase p computes quadrant (MH, KH) of dbuf D: 16 MFMA; B-frags persist
// across the (MH0,MH1) pair. Stage schedule (1 STG = 2 gload_lds(16B)/thr
// per phase): ph1 A11<-k1, ph2 B11<-k1, ph3 A00<-k2, ph4 B00<-k2,
// ph5 A01<-k2, ph6 B01<-k2, ph7 A10<-k3, ph8 B10<-k3.
// vmcnt(8) (= 4 STGs in flight) at even phases; every read's source STG is
// >= 4 STGs older than the covering wait; every restage is after its last
// reader's WAITK. Bank pattern: read chunk = g16 ^ ((fr>>1)&3) -> 2-way free;
// store side pre-swizzles the global source chunk (lane&3)^((lane>>3)&3).
// ===========================================================================
template <int NKT>
__device__ __forceinline__ void gemm8_core(
    const unsigned short* __restrict__ Ag,
    const unsigned short* __restrict__ Bg,
    const int ldk, unsigned short* lds, f32x4 (&acc)[8][4]) {
  const int tid = threadIdx.x, lane = tid & 63, wv = tid >> 6;
  const int wr = wv >> 2, wc = wv & 3;   // 2M x 4N waves
  const int g16 = lane >> 4;             // frag K-quarter
  const int fr  = lane & 15;             // frag row
  const int pc  = (g16 ^ ((fr >> 1) & 3)) << 4;  // physical-chunk byte offset

  const int scg = (lane & 3) ^ ((lane >> 3) & 3);
  const size_t srow0 = (size_t)(wv * 16 + (lane >> 2)) * ldk + scg * 8;
  const size_t srowstep = (size_t)128 * ldk;
  const int sdst0 = wv * 512;  // ushorts within slot

#define ASLOT(D, KH) ((D) * 16384 + (KH) * 8192)
#define BSLOT(D, KH) (32768 + (D) * 16384 + (KH) * 8192)
#define STG(PTR, SLOT, KT, KH)                                                \
  {                                                                           \
    const unsigned short* _g = (PTR) + srow0 + (size_t)(KT) * 64 + (KH) * 32; \
    gload_lds16(_g, lds + (SLOT) + sdst0);                                    \
    gload_lds16(_g + srowstep, lds + (SLOT) + 4096 + sdst0);                  \
  }
#define RD8(SLOT, R) \
  (*(const short8*)((const char*)lds + (SLOT) * 2 + (R) * 64 + pc))

  short8 af[4], bf[4];

#define LDA4(D, KH, MH)                                             \
  _Pragma("unroll") for (int m = 0; m < 4; ++m) {                   \
    af[m] = RD8(ASLOT(D, KH), wr * 128 + (MH) * 64 + m * 16 + fr);  \
  }
#define LDB4(D, KH)                                                 \
  _Pragma("unroll") for (int n = 0; n < 4; ++n) {                   \
    bf[n] = RD8(BSLOT(D, KH), wc * 64 + n * 16 + fr);               \
  }
#define MFMAQ(MH)                                                    \
  __builtin_amdgcn_s_setprio(1);                                     \
  _Pragma("unroll") for (int m = 0; m < 4; ++m)                      \
  _Pragma("unroll") for (int n = 0; n < 4; ++n) {                    \
    acc[(MH) * 4 + m][n] = __builtin_amdgcn_mfma_f32_16x16x32_bf16(  \
        af[m], bf[n], acc[(MH) * 4 + m][n], 0, 0, 0);                \
  }                                                                  \
  __builtin_amdgcn_s_setprio(0);
#define WAITK()                                        \
  asm volatile("s_waitcnt lgkmcnt(0)" ::: "memory");   \
  __builtin_amdgcn_sched_barrier(0);
#define VM8() asm volatile("s_waitcnt vmcnt(8)" ::: "memory")
#define BAR() __builtin_amdgcn_s_barrier()

  // prologue: KT0 {A00,B00,A01,B01} + KT1 {A10,B10}  (6 STGs = 12 loads)
  STG(Ag, ASLOT(0, 0), 0, 0); STG(Bg, BSLOT(0, 0), 0, 0);
  STG(Ag, ASLOT(0, 1), 0, 1); STG(Bg, BSLOT(0, 1), 0, 1);
  STG(Ag, ASLOT(1, 0), 1, 0); STG(Bg, BSLOT(1, 0), 1, 0);
  VM8();  // oldest 2 STGs (A00,B00) landed
  BAR();

  for (int it = 0; it < NKT / 2; ++it) {
    const int k1 = (2 * it + 1) & (NKT - 1);
    const int k2 = (2 * it + 2) & (NKT - 1);  // wrap: uniform counts, no tail
    const int k3 = (2 * it + 3) & (NKT - 1);
    // ph1: (d0,kh0,mh0); stage A11<-k1
    LDA4(0, 0, 0); LDB4(0, 0); STG(Ag, ASLOT(1, 1), k1, 1);
    BAR(); WAITK(); MFMAQ(0); BAR();
    // ph2: (d0,kh0,mh1); stage B11<-k1
    LDA4(0, 0, 1); STG(Bg, BSLOT(1, 1), k1, 1);
    VM8(); BAR(); WAITK(); MFMAQ(1); BAR();
    // ph3: (d0,kh1,mh0); stage A00<-k2
    LDA4(0, 1, 0); LDB4(0, 1); STG(Ag, ASLOT(0, 0), k2, 0);
    BAR(); WAITK(); MFMAQ(0); BAR();
    // ph4: (d0,kh1,mh1); stage B00<-k2
    LDA4(0, 1, 1); STG(Bg, BSLOT(0, 0), k2, 0);
    VM8(); BAR(); WAITK(); MFMAQ(1); BAR();
    // ph5: (d1,kh0,mh0); stage A01<-k2
    LDA4(1, 0, 0); LDB4(1, 0); STG(Ag, ASLOT(0, 1), k2, 1);
    BAR(); WAITK(); MFMAQ(0); BAR();
    // ph6: (d1,kh0,mh1); stage B01<-k2
    LDA4(1, 0, 1); STG(Bg, BSLOT(0, 1), k2, 1);
    VM8(); BAR(); WAITK(); MFMAQ(1); BAR();
    // ph7: (d1,kh1,mh0); stage A10<-k3
    LDA4(1, 1, 0); LDB4(1, 1); STG(Ag, ASLOT(1, 0), k3, 0);
    BAR(); WAITK(); MFMAQ(0); BAR();
    // ph8: (d1,kh1,mh1); stage B10<-k3
    LDA4(1, 1, 1); STG(Bg, BSLOT(1, 0), k3, 0);
    VM8(); BAR(); WAITK(); MFMAQ(1); BAR();
  }
  asm volatile("s_waitcnt vmcnt(0)" ::: "memory");
#undef ASLOT
#undef BSLOT
#undef STG
#undef RD8
#undef LDA4
#undef LDB4
#undef MFMAQ
#undef WAITK
#undef VM8
#undef BAR
}

// Stage 1 (8-phase): eoT[b][o][e][c] = sum_i W[e,o,i]*x[b,e,c,i] + bias[o]
// Per (b,e): M=O=4096 (A=W[e]), N=C=512 (B=x[b,e]), K=NI=512.
__global__ __launch_bounds__(512, 2) void k_gemm1p(
    const unsigned short* __restrict__ Wb, const unsigned short* __restrict__ xb,
    const float* __restrict__ bias, unsigned short* __restrict__ eoT) {
  const int bid = (blockIdx.x & 7) * 128 + (blockIdx.x >> 3);  // bijective, 1024%8==0
  const int be = bid >> 5, tile = bid & 31;
  const int b = be >> 3, e = be & 7;
  const int bm = tile >> 1, bn = tile & 1;

  const int tid = threadIdx.x, lane = tid & 63, wv = tid >> 6;
  const int wr = wv >> 2, wc = wv & 3;
  const int g16 = lane >> 4, fr = lane & 15;

  const unsigned short* Ag = Wb + (size_t)e * NO * NI + (size_t)(bm * 256) * NI;
  const unsigned short* Bg = xb + ((size_t)b * NE + e) * NC * NI + (size_t)(bn * 256) * NI;

  __shared__ __align__(16) unsigned short lds[65536];  // 128 KB

  f32x4 acc[8][4];
#pragma unroll
  for (int m = 0; m < 8; ++m)
#pragma unroll
    for (int n = 0; n < 4; ++n) acc[m][n] = (f32x4)0.f;

  gemm8_core<NI / 64>(Ag, Bg, NI, lds, acc);

  const int o0 = bm * 256 + wr * 128;
  const int c0 = bn * 256 + wc * 64;
#pragma unroll
  for (int i = 0; i < 8; ++i) {
#pragma unroll
    for (int j = 0; j < 4; ++j) {
      const int o = o0 + (i >> 2) * 64 + (i & 3) * 16 + g16 * 4 + j;
      const float bv = bias[o];
      const size_t base = (((size_t)b * NO + o) * NE + e) * NC + c0;
#pragma unroll
      for (int n = 0; n < 4; ++n)
        eoT[base + n * 16 + fr] = f2bf(acc[i][n][j] + bv);
    }
  }
}

// Stage 2 (8-phase): out[b,t,o] = sum_{ec} comb[b,t,e,c] * eoT[b,o,e,c]
__global__ __launch_bounds__(512, 2) void k_gemm2p(
    const unsigned short* __restrict__ cb, const unsigned short* __restrict__ eoT,
    float* __restrict__ out) {
  const int bid = (blockIdx.x & 7) * 64 + (blockIdx.x >> 3);  // 512%8==0
  const int b  = bid >> 7;
  const int bm = (bid >> 4) & 7;
  const int bn = bid & 15;

  const int tid = threadIdx.x, lane = tid & 63, wv = tid >> 6;
  const int wr = wv >> 2, wc = wv & 3;
  const int g16 = lane >> 4, fr = lane & 15;

  const unsigned short* Ag = cb  + (size_t)b * NT * NEC + (size_t)(bm * 256) * NEC;
  const unsigned short* Bg = eoT + (size_t)b * NO * NEC + (size_t)(bn * 256) * NEC;

  __shared__ __align__(16) unsigned short lds[65536];  // 128 KB

  f32x4 acc[8][4];
#pragma unroll
  for (int m = 0; m < 8; ++m)
#pragma unroll
    for (int n = 0; n < 4; ++n) acc[m][n] = (f32x4)0.f;

  gemm8_core<NEC / 64>(Ag, Bg, NEC, lds, acc);

  const int t0 = bm * 256 + wr * 128;
  const int o0 = bn * 256 + wc * 64;
#pragma unroll
  for (int i = 0; i < 8; ++i) {
#pragma unroll
    for (int j = 0; j < 4; ++j) {
      const int t = t0 + (i >> 2) * 64 + (i & 3) * 16 + g16 * 4 + j;
      float* op = out + ((size_t)b * NT + t) * NO + o0;
#pragma unroll
      for (int n = 0; n < 4; ++n) op[n * 16 + fr] = acc[i][n][j];
    }
  }
}

// ===========================================================================
// FALLBACK (round-4 verified) — used when ws_size < 201 MB
// ===========================================================================
__global__ __launch_bounds__(256, 2) void k_gemm1(
    const float* __restrict__ x, const float* __restrict__ W,
    const float* __restrict__ bias, unsigned short* __restrict__ eoT) {
  const int tile = blockIdx.x;
  const int e = blockIdx.y, b = blockIdx.z;
  const int bm = tile >> 2, bn = tile & 3;
  const int tid = threadIdx.x, lane = tid & 63, wv = tid >> 6;
  const int wr = wv >> 1, wc = wv & 1;

  const float* Ag = W + (size_t)e * NO * NI + (size_t)(bm * 128) * NI;
  const float* Bg = x + ((size_t)b * NE + e) * NC * NI + (size_t)(bn * 128) * NI;

  __shared__ __align__(16) unsigned short As[128 * 32];
  __shared__ __align__(16) unsigned short Bs[128 * 32];

  f32x4 acc[4][4];
#pragma unroll
  for (int m = 0; m < 4; ++m)
#pragma unroll
    for (int n = 0; n < 4; ++n) acc[m][n] = (f32x4)0.f;

  for (int k0 = 0; k0 < NI; k0 += 32) {
    __syncthreads();
#pragma unroll
    for (int s = 0; s < 2; ++s) {
      const int q = tid + s * 256;
      const int row = q >> 2, kc = (q & 3) * 8;
      const float* ga = Ag + (size_t)row * NI + k0 + kc;
      float4 a0 = *(const float4*)ga;
      float4 a1 = *(const float4*)(ga + 4);
      *(ushort8*)((char*)As + lds_byte(row, kc * 2)) = cvt8(a0, a1);
      const float* gb = Bg + (size_t)row * NI + k0 + kc;
      float4 b0 = *(const float4*)gb;
      float4 b1 = *(const float4*)(gb + 4);
      *(ushort8*)((char*)Bs + lds_byte(row, kc * 2)) = cvt8(b0, b1);
    }
    __syncthreads();

    const int kb = (lane >> 4) * 16;
    short8 af[4], bfv[4];
#pragma unroll
    for (int m = 0; m < 4; ++m) {
      const int r = wr * 64 + m * 16 + (lane & 15);
      af[m] = *(const short8*)((const char*)As + lds_byte(r, kb));
    }
#pragma unroll
    for (int n = 0; n < 4; ++n) {
      const int r = wc * 64 + n * 16 + (lane & 15);
      bfv[n] = *(const short8*)((const char*)Bs + lds_byte(r, kb));
    }
#pragma unroll
    for (int m = 0; m < 4; ++m)
#pragma unroll
      for (int n = 0; n < 4; ++n)
        acc[m][n] = __builtin_amdgcn_mfma_f32_16x16x32_bf16(
            af[m], bfv[n], acc[m][n], 0, 0, 0);
  }

  const int o0 = bm * 128 + wr * 64;
  const int c0 = bn * 128 + wc * 64;
#pragma unroll
  for (int m = 0; m < 4; ++m) {
#pragma unroll
    for (int j = 0; j < 4; ++j) {
      const int o = o0 + m * 16 + (lane >> 4) * 4 + j;
      const float bv = bias[o];
      const size_t base = (((size_t)b * NO + o) * NE + e) * NC + c0;
#pragma unroll
      for (int n = 0; n < 4; ++n)
        eoT[base + n * 16 + (lane & 15)] = f2bf(acc[m][n][j] + bv);
    }
  }
}

__global__ __launch_bounds__(256, 2) void k_gemm2(
    const float* __restrict__ comb, const unsigned short* __restrict__ eoT,
    float* __restrict__ out) {
  const int b = blockIdx.y;
  const int bm = blockIdx.x >> 5;
  const int bn = blockIdx.x & 31;
  const int tid = threadIdx.x, lane = tid & 63, wv = tid >> 6;
  const int wr = wv >> 1, wc = wv & 1;

  const float* Ag = comb + (size_t)b * NT * NEC + (size_t)(bm * 128) * NEC;
  const unsigned short* Bg = eoT + (size_t)b * NO * NEC + (size_t)(bn * 128) * NEC;

  __shared__ __align__(16) unsigned short As[128 * 32];
  __shared__ __align__(16) unsigned short Bs[128 * 32];

  f32x4 acc[4][4];
#pragma unroll
  for (int m = 0; m < 4; ++m)
#pragma unroll
    for (int n = 0; n < 4; ++n) acc[m][n] = (f32x4)0.f;

  for (int k0 = 0; k0 < NEC; k0 += 32) {
    __syncthreads();
#pragma unroll
    for (int s = 0; s < 2; ++s) {
      const int q = tid + s * 256;
      const int row = q >> 2, kc = (q & 3) * 8;
      const float* ga = Ag + (size_t)row * NEC + k0 + kc;
      float4 a0 = *(const float4*)ga;
      float4 a1 = *(const float4*)(ga + 4);
      *(ushort8*)((char*)As + lds_byte(row, kc * 2)) = cvt8(a0, a1);
      ushort8 bv = *(const ushort8*)(Bg + (size_t)row * NEC + k0 + kc);
      *(ushort8*)((char*)Bs + lds_byte(row, kc * 2)) = bv;
    }
    __syncthreads();

    const int kb = (lane >> 4) * 16;
    short8 af[4], bfv[4];
#pragma unroll
    for (int m = 0; m < 4; ++m) {
      const int r = wr * 64 + m * 16 + (lane & 15);
      af[m] = *(const short8*)((const char*)As + lds_byte(r, kb));
    }
#pragma unroll
    for (int n = 0; n < 4; ++n) {
      const int r = wc * 64 + n * 16 + (lane & 15);
      bfv[n] = *(const short8*)((const char*)Bs + lds_byte(r, kb));
    }
#pragma unroll
    for (int m = 0; m < 4; ++m)
#pragma unroll
      for (int n = 0; n < 4; ++n)
        acc[m][n] = __builtin_amdgcn_mfma_f32_16x16x32_bf16(
            af[m], bfv[n], acc[m][n], 0, 0, 0);
  }

  const int t0 = bm * 128 + wr * 64;
  const int o0 = bn * 128 + wc * 64;
#pragma unroll
  for (int m = 0; m < 4; ++m) {
#pragma unroll
    for (int j = 0; j < 4; ++j) {
      const int t = t0 + m * 16 + (lane >> 4) * 4 + j;
      float* op = out + ((size_t)b * NT + t) * NO + o0;
#pragma unroll
      for (int n = 0; n < 4; ++n) op[n * 16 + (lane & 15)] = acc[m][n][j];
    }
  }
}

extern "C" void kernel_launch(void* const* d_in, const int* in_sizes, int n_in,
                              void* d_out, int out_size, void* d_ws, size_t ws_size,
                              hipStream_t stream) {
  const float* x    = (const float*)d_in[0];  // [B,E,C,I]
  const float* comb = (const float*)d_in[1];  // [B,T,E,C]
  const float* W    = (const float*)d_in[2];  // [E,O,I]
  const float* bias = (const float*)d_in[3];  // [O]
  float* out = (float*)d_out;                 // [B,T,O]

  const size_t EOT_ELEMS = (size_t)NB * NO * NE * NC;   // 67,108,864
  const size_t X_ELEMS   = (size_t)NB * NE * NC * NI;   //  8,388,608
  const size_t W_ELEMS   = (size_t)NE * NO * NI;        // 16,777,216
  const size_t C_ELEMS   = (size_t)NB * NT * NE * NC;   // 33,554,432
  const size_t region2_elems = (C_ELEMS > X_ELEMS + W_ELEMS) ? C_ELEMS : (X_ELEMS + W_ELEMS);
  const size_t need = (EOT_ELEMS + region2_elems) * 2;  // 201,326,592 B

  unsigned short* eoT = (unsigned short*)d_ws;

  if (ws_size >= need) {
    unsigned short* reg2 = eoT + EOT_ELEMS;
    unsigned short* xb = reg2;
    unsigned short* Wb = reg2 + X_ELEMS;
    unsigned short* cbp = reg2;

    k_cvt<<<2048, 256, 0, stream>>>(x, xb, (int)(X_ELEMS / 8));
    k_cvt<<<2048, 256, 0, stream>>>(W, Wb, (int)(W_ELEMS / 8));
    k_gemm1p<<<1024, 512, 0, stream>>>(Wb, xb, bias, eoT);
    k_cvt<<<2048, 256, 0, stream>>>(comb, cbp, (int)(C_ELEMS / 8));
    k_gemm2p<<<512, 512, 0, stream>>>(cbp, eoT, out);
  } else {
    k_gemm1<<<dim3(128, NE, NB), 256, 0, stream>>>(x, W, bias, eoT);
    k_gemm2<<<dim3(512, NB), 256, 0, stream>>>(comb, eoT, out);
  }
}

// Round 11
// 396.616 us; speedup vs baseline: 1.3332x; 1.0179x over previous
//
#include <hip/hip_runtime.h>
#include <hip/hip_bf16.h>
#include <cstdint>

// Problem constants: B,T,E,C,I_E,O = 4,2048,8,512,512,4096
constexpr int NB = 4;
constexpr int NT = 2048;
constexpr int NE = 8;
constexpr int NC = 512;
constexpr int NI = 512;
constexpr int NO = 4096;
constexpr int NEC = NE * NC;  // 4096 (stage-2 K)

typedef __attribute__((ext_vector_type(8))) short short8;
typedef __attribute__((ext_vector_type(8))) unsigned short ushort8;
typedef __attribute__((ext_vector_type(4))) float f32x4;

__device__ __forceinline__ unsigned short f2bf(float f) {
  unsigned int u = __builtin_bit_cast(unsigned int, f);
  u += 0x7FFFu + ((u >> 16) & 1u);
  return (unsigned short)(u >> 16);
}

__device__ __forceinline__ ushort8 cvt8(float4 a, float4 b) {
  ushort8 v;
  v[0] = f2bf(a.x); v[1] = f2bf(a.y); v[2] = f2bf(a.z); v[3] = f2bf(a.w);
  v[4] = f2bf(b.x); v[5] = f2bf(b.y); v[6] = f2bf(b.z); v[7] = f2bf(b.w);
  return v;
}

// swizzle for the fallback 128x32 tiles
__device__ __forceinline__ int lds_byte(int row, int kbyte) {
  return (row * 64 + kbyte) ^ ((row & 6) << 3);
}

__device__ __forceinline__ void gload_lds16(const void* g, void* lds) {
  __builtin_amdgcn_global_load_lds(
      (const __attribute__((address_space(1))) unsigned int*)g,
      (__attribute__((address_space(3))) unsigned int*)lds, 16, 0, 0);
}

// f32 -> bf16 conversion, 8 elems/thread/iter, grid-stride
__global__ __launch_bounds__(256) void k_cvt(
    const float* __restrict__ src, unsigned short* __restrict__ dst, int n8) {
  int i = blockIdx.x * blockDim.x + threadIdx.x;
  const int stride = gridDim.x * blockDim.x;
  for (; i < n8; i += stride) {
    const float4* s = (const float4*)(src + (size_t)i * 8);
    float4 a = s[0], b = s[1];
    *(ushort8*)(dst + (size_t)i * 8) = cvt8(a, b);
  }
}

// ===========================================================================
// 256x256 8-phase READ-AHEAD pipeline core.
// Per phase: STG(slot) ; [VM6 if odd] ; issue rd(p+1) -> alternate regset ;
// counted lgkm (drain rd(p), leave rd(p+1) in flight) ; MFMA(p) ; BAR.
// Fragment reads for p+1 execute on the LDS pipe DURING MFMA(p).
// VM6 at odd phases covers the slot pair read-issued at the following even
// phase (BAR-separated, so cross-wave landing is guaranteed). One barrier
// per phase. Counted-lgkm relies on in-order DS returns (HK-verified).
// Stage schedule unchanged from r9: ph1 A11<-k1, ph2 B11<-k1, ph3 A00<-k2,
// ph4 B00<-k2, ph5 A01<-k2, ph6 B01<-k2, ph7 A10<-k3, ph8 B10<-k3.
// Bank pattern: read chunk = g16 ^ ((fr>>1)&3) (2-way, free); source chunk
// pre-swizzled (lane&3)^((lane>>3)&3). Verified conflict-free in r9 (PMC=0).
// ===========================================================================
template <int NKT>
__device__ __forceinline__ void gemm8_core(
    const unsigned short* __restrict__ Ag,
    const unsigned short* __restrict__ Bg,
    const int ldk, unsigned short* lds, f32x4 (&acc)[8][4]) {
  const int tid = threadIdx.x, lane = tid & 63, wv = tid >> 6;
  const int wr = wv >> 2, wc = wv & 3;   // 2M x 4N waves
  const int g16 = lane >> 4;             // frag K-quarter
  const int fr  = lane & 15;             // frag row
  const int pc  = (g16 ^ ((fr >> 1) & 3)) << 4;  // physical-chunk byte offset

  const int scg = (lane & 3) ^ ((lane >> 3) & 3);
  const size_t srow0 = (size_t)(wv * 16 + (lane >> 2)) * ldk + scg * 8;
  const size_t srowstep = (size_t)128 * ldk;
  const int sdst0 = wv * 512;  // ushorts within slot

#define ASLOT(D, KH) ((D) * 16384 + (KH) * 8192)
#define BSLOT(D, KH) (32768 + (D) * 16384 + (KH) * 8192)
#define STG(PTR, SLOT, KT, KH)                                                \
  {                                                                           \
    const unsigned short* _g = (PTR) + srow0 + (size_t)(KT) * 64 + (KH) * 32; \
    gload_lds16(_g, lds + (SLOT) + sdst0);                                    \
    gload_lds16(_g + srowstep, lds + (SLOT) + 4096 + sdst0);                  \
  }
#define RD8(SLOT, R) \
  (*(const short8*)((const char*)lds + (SLOT) * 2 + (R) * 64 + pc))

  short8 afA[4], afB[4], bfA[4], bfB[4];

#define LDA4(SET, D, KH, MH)                                        \
  _Pragma("unroll") for (int m = 0; m < 4; ++m) {                   \
    SET[m] = RD8(ASLOT(D, KH), wr * 128 + (MH) * 64 + m * 16 + fr); \
  }
#define LDB4(SET, D, KH)                                            \
  _Pragma("unroll") for (int n = 0; n < 4; ++n) {                   \
    SET[n] = RD8(BSLOT(D, KH), wc * 64 + n * 16 + fr);              \
  }
#define MFMAQ(ASET, BSET, MH)                                        \
  __builtin_amdgcn_s_setprio(1);                                     \
  _Pragma("unroll") for (int m = 0; m < 4; ++m)                      \
  _Pragma("unroll") for (int n = 0; n < 4; ++n) {                    \
    acc[(MH) * 4 + m][n] = __builtin_amdgcn_mfma_f32_16x16x32_bf16(  \
        ASET[m], BSET[n], acc[(MH) * 4 + m][n], 0, 0, 0);            \
  }                                                                  \
  __builtin_amdgcn_s_setprio(0);
#define LG4()                                          \
  asm volatile("s_waitcnt lgkmcnt(4)" ::: "memory");   \
  __builtin_amdgcn_sched_barrier(0)
#define LG8()                                          \
  asm volatile("s_waitcnt lgkmcnt(8)" ::: "memory");   \
  __builtin_amdgcn_sched_barrier(0)
#define VM6() asm volatile("s_waitcnt vmcnt(6)" ::: "memory")
#define BAR() __builtin_amdgcn_s_barrier()

  // prologue: stage slots in prev-S3..prev-S8 roles: A00,B00,A01,B01,A10,B10
  STG(Ag, ASLOT(0, 0), 0, 0); STG(Bg, BSLOT(0, 0), 0, 0);
  STG(Ag, ASLOT(0, 1), 0, 1); STG(Bg, BSLOT(0, 1), 0, 1);
  STG(Ag, ASLOT(1, 0), 1, 0); STG(Bg, BSLOT(1, 0), 1, 0);
  asm volatile("s_waitcnt vmcnt(8)" ::: "memory");  // A00,B00 landed
  BAR();
  LDA4(afA, 0, 0, 0); LDB4(bfA, 0, 0);  // rd(ph1)

  for (int it = 0; it < NKT / 2; ++it) {
    const int k1 = (2 * it + 1) & (NKT - 1);
    const int k2 = (2 * it + 2) & (NKT - 1);  // wrap: uniform counts, no tail
    const int k3 = (2 * it + 3) & (NKT - 1);
    // ph1: compute (d0,k0,m0)[afA,bfA]; S1=A11<-k1; VM6; rd(ph2)->afB
    STG(Ag, ASLOT(1, 1), k1, 1);
    VM6();
    LDA4(afB, 0, 0, 1);
    LG4();
    MFMAQ(afA, bfA, 0);
    BAR();
    // ph2: (d0,k0,m1)[afB,bfA]; S2=B11<-k1; rd(ph3)->afA,bfB
    STG(Bg, BSLOT(1, 1), k1, 1);
    LDA4(afA, 0, 1, 0); LDB4(bfB, 0, 1);
    LG8();
    MFMAQ(afB, bfA, 1);
    BAR();
    // ph3: (d0,k1,m0)[afA,bfB]; S3=A00<-k2; VM6; rd(ph4)->afB
    STG(Ag, ASLOT(0, 0), k2, 0);
    VM6();
    LDA4(afB, 0, 1, 1);
    LG4();
    MFMAQ(afA, bfB, 0);
    BAR();
    // ph4: (d0,k1,m1)[afB,bfB]; S4=B00<-k2; rd(ph5)->afA,bfA
    STG(Bg, BSLOT(0, 0), k2, 0);
    LDA4(afA, 1, 0, 0); LDB4(bfA, 1, 0);
    LG8();
    MFMAQ(afB, bfB, 1);
    BAR();
    // ph5: (d1,k0,m0)[afA,bfA]; S5=A01<-k2; VM6; rd(ph6)->afB
    STG(Ag, ASLOT(0, 1), k2, 1);
    VM6();
    LDA4(afB, 1, 0, 1);
    LG4();
    MFMAQ(afA, bfA, 0);
    BAR();
    // ph6: (d1,k0,m1)[afB,bfA]; S6=B01<-k2; rd(ph7)->afA,bfB
    STG(Bg, BSLOT(0, 1), k2, 1);
    LDA4(afA, 1, 1, 0); LDB4(bfB, 1, 1);
    LG8();
    MFMAQ(afB, bfA, 1);
    BAR();
    // ph7: (d1,k1,m0)[afA,bfB]; S7=A10<-k3; VM6; rd(ph8)->afB
    STG(Ag, ASLOT(1, 0), k3, 0);
    VM6();
    LDA4(afB, 1, 1, 1);
    LG4();
    MFMAQ(afA, bfB, 0);
    BAR();
    // ph8: (d1,k1,m1)[afB,bfB]; S8=B10<-k3; rd(ph1')->afA,bfA
    STG(Bg, BSLOT(1, 0), k3, 0);
    LDA4(afA, 0, 0, 0); LDB4(bfA, 0, 0);
    LG8();
    MFMAQ(afB, bfB, 1);
    BAR();
  }
  asm volatile("s_waitcnt vmcnt(0) lgkmcnt(0)" ::: "memory");
#undef ASLOT
#undef BSLOT
#undef STG
#undef RD8
#undef LDA4
#undef LDB4
#undef MFMAQ
#undef LG4
#undef LG8
#undef VM6
#undef BAR
}

// Stage 1 (8-phase): eoT[b][o][e][c] = sum_i W[e,o,i]*x[b,e,c,i] + bias[o]
__global__ __launch_bounds__(512, 2) void k_gemm1p(
    const unsigned short* __restrict__ Wb, const unsigned short* __restrict__ xb,
    const float* __restrict__ bias, unsigned short* __restrict__ eoT) {
  const int bid = (blockIdx.x & 7) * 128 + (blockIdx.x >> 3);  // bijective, 1024%8==0
  const int be = bid >> 5, tile = bid & 31;
  const int b = be >> 3, e = be & 7;
  const int bm = tile >> 1, bn = tile & 1;

  const int tid = threadIdx.x, lane = tid & 63, wv = tid >> 6;
  const int wr = wv >> 2, wc = wv & 3;
  const int g16 = lane >> 4, fr = lane & 15;

  const unsigned short* Ag = Wb + (size_t)e * NO * NI + (size_t)(bm * 256) * NI;
  const unsigned short* Bg = xb + ((size_t)b * NE + e) * NC * NI + (size_t)(bn * 256) * NI;

  __shared__ __align__(16) unsigned short lds[65536];  // 128 KB

  f32x4 acc[8][4];
#pragma unroll
  for (int m = 0; m < 8; ++m)
#pragma unroll
    for (int n = 0; n < 4; ++n) acc[m][n] = (f32x4)0.f;

  gemm8_core<NI / 64>(Ag, Bg, NI, lds, acc);

  const int o0 = bm * 256 + wr * 128;
  const int c0 = bn * 256 + wc * 64;
#pragma unroll
  for (int i = 0; i < 8; ++i) {
#pragma unroll
    for (int j = 0; j < 4; ++j) {
      const int o = o0 + (i >> 2) * 64 + (i & 3) * 16 + g16 * 4 + j;
      const float bv = bias[o];
      const size_t base = (((size_t)b * NO + o) * NE + e) * NC + c0;
#pragma unroll
      for (int n = 0; n < 4; ++n)
        eoT[base + n * 16 + fr] = f2bf(acc[i][n][j] + bv);
    }
  }
}

// Stage 2 (8-phase): out[b,t,o] = sum_{ec} comb[b,t,e,c] * eoT[b,o,e,c]
__global__ __launch_bounds__(512, 2) void k_gemm2p(
    const unsigned short* __restrict__ cb, const unsigned short* __restrict__ eoT,
    float* __restrict__ out) {
  const int bid = (blockIdx.x & 7) * 64 + (blockIdx.x >> 3);  // 512%8==0
  const int b  = bid >> 7;
  const int bm = (bid >> 4) & 7;
  const int bn = bid & 15;

  const int tid = threadIdx.x, lane = tid & 63, wv = tid >> 6;
  const int wr = wv >> 2, wc = wv & 3;
  const int g16 = lane >> 4, fr = lane & 15;

  const unsigned short* Ag = cb  + (size_t)b * NT * NEC + (size_t)(bm * 256) * NEC;
  const unsigned short* Bg = eoT + (size_t)b * NO * NEC + (size_t)(bn * 256) * NEC;

  __shared__ __align__(16) unsigned short lds[65536];  // 128 KB

  f32x4 acc[8][4];
#pragma unroll
  for (int m = 0; m < 8; ++m)
#pragma unroll
    for (int n = 0; n < 4; ++n) acc[m][n] = (f32x4)0.f;

  gemm8_core<NEC / 64>(Ag, Bg, NEC, lds, acc);

  const int t0 = bm * 256 + wr * 128;
  const int o0 = bn * 256 + wc * 64;
#pragma unroll
  for (int i = 0; i < 8; ++i) {
#pragma unroll
    for (int j = 0; j < 4; ++j) {
      const int t = t0 + (i >> 2) * 64 + (i & 3) * 16 + g16 * 4 + j;
      float* op = out + ((size_t)b * NT + t) * NO + o0;
#pragma unroll
      for (int n = 0; n < 4; ++n) op[n * 16 + fr] = acc[i][n][j];
    }
  }
}

// ===========================================================================
// FALLBACK (round-4 verified) — used when ws_size < 201 MB
// ===========================================================================
__global__ __launch_bounds__(256, 2) void k_gemm1(
    const float* __restrict__ x, const float* __restrict__ W,
    const float* __restrict__ bias, unsigned short* __restrict__ eoT) {
  const int tile = blockIdx.x;
  const int e = blockIdx.y, b = blockIdx.z;
  const int bm = tile >> 2, bn = tile & 3;
  const int tid = threadIdx.x, lane = tid & 63, wv = tid >> 6;
  const int wr = wv >> 1, wc = wv & 1;

  const float* Ag = W + (size_t)e * NO * NI + (size_t)(bm * 128) * NI;
  const float* Bg = x + ((size_t)b * NE + e) * NC * NI + (size_t)(bn * 128) * NI;

  __shared__ __align__(16) unsigned short As[128 * 32];
  __shared__ __align__(16) unsigned short Bs[128 * 32];

  f32x4 acc[4][4];
#pragma unroll
  for (int m = 0; m < 4; ++m)
#pragma unroll
    for (int n = 0; n < 4; ++n) acc[m][n] = (f32x4)0.f;

  for (int k0 = 0; k0 < NI; k0 += 32) {
    __syncthreads();
#pragma unroll
    for (int s = 0; s < 2; ++s) {
      const int q = tid + s * 256;
      const int row = q >> 2, kc = (q & 3) * 8;
      const float* ga = Ag + (size_t)row * NI + k0 + kc;
      float4 a0 = *(const float4*)ga;
      float4 a1 = *(const float4*)(ga + 4);
      *(ushort8*)((char*)As + lds_byte(row, kc * 2)) = cvt8(a0, a1);
      const float* gb = Bg + (size_t)row * NI + k0 + kc;
      float4 b0 = *(const float4*)gb;
      float4 b1 = *(const float4*)(gb + 4);
      *(ushort8*)((char*)Bs + lds_byte(row, kc * 2)) = cvt8(b0, b1);
    }
    __syncthreads();

    const int kb = (lane >> 4) * 16;
    short8 af[4], bfv[4];
#pragma unroll
    for (int m = 0; m < 4; ++m) {
      const int r = wr * 64 + m * 16 + (lane & 15);
      af[m] = *(const short8*)((const char*)As + lds_byte(r, kb));
    }
#pragma unroll
    for (int n = 0; n < 4; ++n) {
      const int r = wc * 64 + n * 16 + (lane & 15);
      bfv[n] = *(const short8*)((const char*)Bs + lds_byte(r, kb));
    }
#pragma unroll
    for (int m = 0; m < 4; ++m)
#pragma unroll
      for (int n = 0; n < 4; ++n)
        acc[m][n] = __builtin_amdgcn_mfma_f32_16x16x32_bf16(
            af[m], bfv[n], acc[m][n], 0, 0, 0);
  }

  const int o0 = bm * 128 + wr * 64;
  const int c0 = bn * 128 + wc * 64;
#pragma unroll
  for (int m = 0; m < 4; ++m) {
#pragma unroll
    for (int j = 0; j < 4; ++j) {
      const int o = o0 + m * 16 + (lane >> 4) * 4 + j;
      const float bv = bias[o];
      const size_t base = (((size_t)b * NO + o) * NE + e) * NC + c0;
#pragma unroll
      for (int n = 0; n < 4; ++n)
        eoT[base + n * 16 + (lane & 15)] = f2bf(acc[m][n][j] + bv);
    }
  }
}

__global__ __launch_bounds__(256, 2) void k_gemm2(
    const float* __restrict__ comb, const unsigned short* __restrict__ eoT,
    float* __restrict__ out) {
  const int b = blockIdx.y;
  const int bm = blockIdx.x >> 5;
  const int bn = blockIdx.x & 31;
  const int tid = threadIdx.x, lane = tid & 63, wv = tid >> 6;
  const int wr = wv >> 1, wc = wv & 1;

  const float* Ag = comb + (size_t)b * NT * NEC + (size_t)(bm * 128) * NEC;
  const unsigned short* Bg = eoT + (size_t)b * NO * NEC + (size_t)(bn * 128) * NEC;

  __shared__ __align__(16) unsigned short As[128 * 32];
  __shared__ __align__(16) unsigned short Bs[128 * 32];

  f32x4 acc[4][4];
#pragma unroll
  for (int m = 0; m < 4; ++m)
#pragma unroll
    for (int n = 0; n < 4; ++n) acc[m][n] = (f32x4)0.f;

  for (int k0 = 0; k0 < NEC; k0 += 32) {
    __syncthreads();
#pragma unroll
    for (int s = 0; s < 2; ++s) {
      const int q = tid + s * 256;
      const int row = q >> 2, kc = (q & 3) * 8;
      const float* ga = Ag + (size_t)row * NEC + k0 + kc;
      float4 a0 = *(const float4*)ga;
      float4 a1 = *(const float4*)(ga + 4);
      *(ushort8*)((char*)As + lds_byte(row, kc * 2)) = cvt8(a0, a1);
      ushort8 bv = *(const ushort8*)(Bg + (size_t)row * NEC + k0 + kc);
      *(ushort8*)((char*)Bs + lds_byte(row, kc * 2)) = bv;
    }
    __syncthreads();

    const int kb = (lane >> 4) * 16;
    short8 af[4], bfv[4];
#pragma unroll
    for (int m = 0; m < 4; ++m) {
      const int r = wr * 64 + m * 16 + (lane & 15);
      af[m] = *(const short8*)((const char*)As + lds_byte(r, kb));
    }
#pragma unroll
    for (int n = 0; n < 4; ++n) {
      const int r = wc * 64 + n * 16 + (lane & 15);
      bfv[n] = *(const short8*)((const char*)Bs + lds_byte(r, kb));
    }
#pragma unroll
    for (int m = 0; m < 4; ++m)
#pragma unroll
      for (int n = 0; n < 4; ++n)
        acc[m][n] = __builtin_amdgcn_mfma_f32_16x16x32_bf16(
            af[m], bfv[n], acc[m][n], 0, 0, 0);
  }

  const int t0 = bm * 128 + wr * 64;
  const int o0 = bn * 128 + wc * 64;
#pragma unroll
  for (int m = 0; m < 4; ++m) {
#pragma unroll
    for (int j = 0; j < 4; ++j) {
      const int t = t0 + m * 16 + (lane >> 4) * 4 + j;
      float* op = out + ((size_t)b * NT + t) * NO + o0;
#pragma unroll
      for (int n = 0; n < 4; ++n) op[n * 16 + (lane & 15)] = acc[m][n][j];
    }
  }
}

extern "C" void kernel_launch(void* const* d_in, const int* in_sizes, int n_in,
                              void* d_out, int out_size, void* d_ws, size_t ws_size,
                              hipStream_t stream) {
  const float* x    = (const float*)d_in[0];  // [B,E,C,I]
  const float* comb = (const float*)d_in[1];  // [B,T,E,C]
  const float* W    = (const float*)d_in[2];  // [E,O,I]
  const float* bias = (const float*)d_in[3];  // [O]
  float* out = (float*)d_out;                 // [B,T,O]

  const size_t EOT_ELEMS = (size_t)NB * NO * NE * NC;   // 67,108,864
  const size_t X_ELEMS   = (size_t)NB * NE * NC * NI;   //  8,388,608
  const size_t W_ELEMS   = (size_t)NE * NO * NI;        // 16,777,216
  const size_t C_ELEMS   = (size_t)NB * NT * NE * NC;   // 33,554,432
  const size_t region2_elems = (C_ELEMS > X_ELEMS + W_ELEMS) ? C_ELEMS : (X_ELEMS + W_ELEMS);
  const size_t need = (EOT_ELEMS + region2_elems) * 2;  // 201,326,592 B

  unsigned short* eoT = (unsigned short*)d_ws;

  if (ws_size >= need) {
    unsigned short* reg2 = eoT + EOT_ELEMS;
    unsigned short* xb = reg2;
    unsigned short* Wb = reg2 + X_ELEMS;
    unsigned short* cbp = reg2;

    k_cvt<<<2048, 256, 0, stream>>>(x, xb, (int)(X_ELEMS / 8));
    k_cvt<<<2048, 256, 0, stream>>>(W, Wb, (int)(W_ELEMS / 8));
    k_gemm1p<<<1024, 512, 0, stream>>>(Wb, xb, bias, eoT);
    k_cvt<<<2048, 256, 0, stream>>>(comb, cbp, (int)(C_ELEMS / 8));
    k_gemm2p<<<512, 512, 0, stream>>>(cbp, eoT, out);
  } else {
    k_gemm1<<<dim3(128, NE, NB), 256, 0, stream>>>(x, W, bias, eoT);
    k_gemm2<<<dim3(512, NB), 256, 0, stream>>>(comb, eoT, out);
  }
}

// Round 12
// 354.387 us; speedup vs baseline: 1.4921x; 1.1192x over previous
//
#include <hip/hip_runtime.h>
#include <hip/hip_bf16.h>
#include <cstdint>

// Problem constants: B,T,E,C,I_E,O = 4,2048,8,512,512,4096
constexpr int NB = 4;
constexpr int NT = 2048;
constexpr int NE = 8;
constexpr int NC = 512;
constexpr int NI = 512;
constexpr int NO = 4096;
constexpr int NEC = NE * NC;   // 4096
constexpr int NEI = NE * NI;   // 4096 (restructured stage-2 K)

typedef __attribute__((ext_vector_type(8))) short short8;
typedef __attribute__((ext_vector_type(8))) unsigned short ushort8;
typedef __attribute__((ext_vector_type(4))) float f32x4;

__device__ __forceinline__ unsigned short f2bf(float f) {
  unsigned int u = __builtin_bit_cast(unsigned int, f);
  u += 0x7FFFu + ((u >> 16) & 1u);
  return (unsigned short)(u >> 16);
}

__device__ __forceinline__ ushort8 cvt8(float4 a, float4 b) {
  ushort8 v;
  v[0] = f2bf(a.x); v[1] = f2bf(a.y); v[2] = f2bf(a.z); v[3] = f2bf(a.w);
  v[4] = f2bf(b.x); v[5] = f2bf(b.y); v[6] = f2bf(b.z); v[7] = f2bf(b.w);
  return v;
}

// swizzle for the fallback 128x32 tiles
__device__ __forceinline__ int lds_byte(int row, int kbyte) {
  return (row * 64 + kbyte) ^ ((row & 6) << 3);
}

__device__ __forceinline__ void gload_lds16(const void* g, void* lds) {
  __builtin_amdgcn_global_load_lds(
      (const __attribute__((address_space(1))) unsigned int*)g,
      (__attribute__((address_space(3))) unsigned int*)lds, 16, 0, 0);
}

// ===========================================================================
// Conversion / permutation passes
// ===========================================================================

// comb f32 [B,T,E,C] -> cbp bf16 (same layout) + S[b*T+t] = row sum (f32)
__global__ __launch_bounds__(256) void k_cvt_comb(
    const float* __restrict__ comb, unsigned short* __restrict__ cbp,
    float* __restrict__ S) {
  const int row = blockIdx.x;  // 8192 rows of 4096
  const float* src = comb + (size_t)row * NEC;
  unsigned short* dst = cbp + (size_t)row * NEC;
  const int tid = threadIdx.x;
  float sum = 0.f;
#pragma unroll
  for (int it = 0; it < 2; ++it) {
    const int i8 = tid + it * 256;
    const float4* s = (const float4*)(src + i8 * 8);
    float4 a = s[0], b4 = s[1];
    *(ushort8*)(dst + i8 * 8) = cvt8(a, b4);
    sum += a.x + a.y + a.z + a.w + b4.x + b4.y + b4.z + b4.w;
  }
  for (int off = 32; off > 0; off >>= 1) sum += __shfl_down(sum, off);
  __shared__ float ws4[4];
  if ((tid & 63) == 0) ws4[tid >> 6] = sum;
  __syncthreads();
  if (tid == 0) S[row] = ws4[0] + ws4[1] + ws4[2] + ws4[3];
}

// x f32 [B,E,C,I] -> xT bf16 [B,E,I,C]  (64x64 LDS-tiled transpose)
__global__ __launch_bounds__(256) void k_cvtT_x(
    const float* __restrict__ x, unsigned short* __restrict__ xT) {
  const int be = blockIdx.x >> 6;    // 32
  const int tile = blockIdx.x & 63;  // 8x8 tiles
  const int c0 = (tile >> 3) * 64, i0 = (tile & 7) * 64;
  const float* src = x + (size_t)be * NC * NI;
  unsigned short* dst = xT + (size_t)be * NI * NC;
  __shared__ unsigned short tl[64][65];
  const int lr = threadIdx.x >> 6, lc = threadIdx.x & 63;
#pragma unroll
  for (int s = 0; s < 16; ++s) {
    const int c = s * 4 + lr;
    tl[c][lc] = f2bf(src[(size_t)(c0 + c) * NI + i0 + lc]);
  }
  __syncthreads();
#pragma unroll
  for (int s = 0; s < 16; ++s) {
    const int i = s * 4 + lr;
    dst[(size_t)(i0 + i) * NC + c0 + lc] = tl[lc][i];
  }
}

// W f32 [E,O,I] -> Wt bf16 [O,E,I]  (coalesced both sides; i innermost)
__global__ __launch_bounds__(256) void k_cvtT_W(
    const float* __restrict__ W, unsigned short* __restrict__ Wt) {
  const size_t n8 = (size_t)NE * NO * NI / 8;  // 2,097,152
  size_t idx = (size_t)blockIdx.x * 256 + threadIdx.x;
  const size_t stride = (size_t)gridDim.x * 256;
  for (; idx < n8; idx += stride) {
    const int i8 = (int)(idx & (NI / 8 - 1));
    const size_t eo = idx >> 6;          // e*O + o
    const int e = (int)(eo >> 12);
    const int o = (int)(eo & 4095);
    const float4* s = (const float4*)(W + eo * NI + i8 * 8);
    float4 a = s[0], b4 = s[1];
    *(ushort8*)(Wt + ((size_t)o * NE + e) * NI + i8 * 8) = cvt8(a, b4);
  }
}

// ===========================================================================
// 256x256 8-phase READ-AHEAD pipeline core (r11-verified schedule).
// Generalized to separate A/B row strides (ldkA, ldkB).
// Per phase: STG(slot); [VM6 odd]; issue rd(p+1)->alt regset; counted lgkm;
// MFMA(p); BAR. Stage schedule: ph1 A11<-k1, ph2 B11<-k1, ph3 A00<-k2,
// ph4 B00<-k2, ph5 A01<-k2, ph6 B01<-k2, ph7 A10<-k3, ph8 B10<-k3.
// Bank pattern (PMC-verified 0 conflicts): read chunk = g16 ^ ((fr>>1)&3);
// source chunk pre-swizzled (lane&3)^((lane>>3)&3).
// ===========================================================================
template <int NKT>
__device__ __forceinline__ void gemm8_core(
    const unsigned short* __restrict__ Ag,
    const unsigned short* __restrict__ Bg,
    const int ldkA, const int ldkB, unsigned short* lds, f32x4 (&acc)[8][4]) {
  const int tid = threadIdx.x, lane = tid & 63, wv = tid >> 6;
  const int wr = wv >> 2, wc = wv & 3;
  const int g16 = lane >> 4;
  const int fr  = lane & 15;
  const int pc  = (g16 ^ ((fr >> 1) & 3)) << 4;

  const int scg = (lane & 3) ^ ((lane >> 3) & 3);
  const size_t srow0A = (size_t)(wv * 16 + (lane >> 2)) * ldkA + scg * 8;
  const size_t srow0B = (size_t)(wv * 16 + (lane >> 2)) * ldkB + scg * 8;
  const size_t srstA = (size_t)128 * ldkA;
  const size_t srstB = (size_t)128 * ldkB;
  const int sdst0 = wv * 512;

#define ASLOT(D, KH) ((D) * 16384 + (KH) * 8192)
#define BSLOT(D, KH) (32768 + (D) * 16384 + (KH) * 8192)
#define STG(PTR, SR0, SRST, SLOT, KT, KH)                                  \
  {                                                                        \
    const unsigned short* _g = (PTR) + (SR0) + (size_t)(KT) * 64 + (KH) * 32; \
    gload_lds16(_g, lds + (SLOT) + sdst0);                                 \
    gload_lds16(_g + (SRST), lds + (SLOT) + 4096 + sdst0);                 \
  }
#define RD8(SLOT, R) \
  (*(const short8*)((const char*)lds + (SLOT) * 2 + (R) * 64 + pc))

  short8 afA[4], afB[4], bfA[4], bfB[4];

#define LDA4(SET, D, KH, MH)                                        \
  _Pragma("unroll") for (int m = 0; m < 4; ++m) {                   \
    SET[m] = RD8(ASLOT(D, KH), wr * 128 + (MH) * 64 + m * 16 + fr); \
  }
#define LDB4(SET, D, KH)                                            \
  _Pragma("unroll") for (int n = 0; n < 4; ++n) {                   \
    SET[n] = RD8(BSLOT(D, KH), wc * 64 + n * 16 + fr);              \
  }
#define MFMAQ(ASET, BSET, MH)                                        \
  __builtin_amdgcn_s_setprio(1);                                     \
  _Pragma("unroll") for (int m = 0; m < 4; ++m)                      \
  _Pragma("unroll") for (int n = 0; n < 4; ++n) {                    \
    acc[(MH) * 4 + m][n] = __builtin_amdgcn_mfma_f32_16x16x32_bf16(  \
        ASET[m], BSET[n], acc[(MH) * 4 + m][n], 0, 0, 0);            \
  }                                                                  \
  __builtin_amdgcn_s_setprio(0);
#define LG4()                                          \
  asm volatile("s_waitcnt lgkmcnt(4)" ::: "memory");   \
  __builtin_amdgcn_sched_barrier(0)
#define LG8()                                          \
  asm volatile("s_waitcnt lgkmcnt(8)" ::: "memory");   \
  __builtin_amdgcn_sched_barrier(0)
#define VM6() asm volatile("s_waitcnt vmcnt(6)" ::: "memory")
#define BAR() __builtin_amdgcn_s_barrier()

  STG(Ag, srow0A, srstA, ASLOT(0, 0), 0, 0);
  STG(Bg, srow0B, srstB, BSLOT(0, 0), 0, 0);
  STG(Ag, srow0A, srstA, ASLOT(0, 1), 0, 1);
  STG(Bg, srow0B, srstB, BSLOT(0, 1), 0, 1);
  STG(Ag, srow0A, srstA, ASLOT(1, 0), 1, 0);
  STG(Bg, srow0B, srstB, BSLOT(1, 0), 1, 0);
  asm volatile("s_waitcnt vmcnt(8)" ::: "memory");
  BAR();
  LDA4(afA, 0, 0, 0); LDB4(bfA, 0, 0);

  for (int it = 0; it < NKT / 2; ++it) {
    const int k1 = (2 * it + 1) & (NKT - 1);
    const int k2 = (2 * it + 2) & (NKT - 1);
    const int k3 = (2 * it + 3) & (NKT - 1);
    STG(Ag, srow0A, srstA, ASLOT(1, 1), k1, 1);
    VM6();
    LDA4(afB, 0, 0, 1);
    LG4();
    MFMAQ(afA, bfA, 0);
    BAR();
    STG(Bg, srow0B, srstB, BSLOT(1, 1), k1, 1);
    LDA4(afA, 0, 1, 0); LDB4(bfB, 0, 1);
    LG8();
    MFMAQ(afB, bfA, 1);
    BAR();
    STG(Ag, srow0A, srstA, ASLOT(0, 0), k2, 0);
    VM6();
    LDA4(afB, 0, 1, 1);
    LG4();
    MFMAQ(afA, bfB, 0);
    BAR();
    STG(Bg, srow0B, srstB, BSLOT(0, 0), k2, 0);
    LDA4(afA, 1, 0, 0); LDB4(bfA, 1, 0);
    LG8();
    MFMAQ(afB, bfB, 1);
    BAR();
    STG(Ag, srow0A, srstA, ASLOT(0, 1), k2, 1);
    VM6();
    LDA4(afB, 1, 0, 1);
    LG4();
    MFMAQ(afA, bfA, 0);
    BAR();
    STG(Bg, srow0B, srstB, BSLOT(0, 1), k2, 1);
    LDA4(afA, 1, 1, 0); LDB4(bfB, 1, 1);
    LG8();
    MFMAQ(afB, bfA, 1);
    BAR();
    STG(Ag, srow0A, srstA, ASLOT(1, 0), k3, 0);
    VM6();
    LDA4(afB, 1, 1, 1);
    LG4();
    MFMAQ(afA, bfB, 0);
    BAR();
    STG(Bg, srow0B, srstB, BSLOT(1, 0), k3, 0);
    LDA4(afA, 0, 0, 0); LDB4(bfA, 0, 0);
    LG8();
    MFMAQ(afB, bfB, 1);
    BAR();
  }
  asm volatile("s_waitcnt vmcnt(0) lgkmcnt(0)" ::: "memory");
#undef ASLOT
#undef BSLOT
#undef STG
#undef RD8
#undef LDA4
#undef LDB4
#undef MFMAQ
#undef LG4
#undef LG8
#undef VM6
#undef BAR
}

// Stage 1': Y[b,t,e*512+i] = sum_c comb[b,t,e,c] * xT[b,e,i,c]   (bf16 out)
// Per (b,e): M=T=2048, N=I=512, K=C=512. A row stride 4096, B row stride 512.
__global__ __launch_bounds__(512, 2) void k_gemm1q(
    const unsigned short* __restrict__ cbp, const unsigned short* __restrict__ xT,
    unsigned short* __restrict__ Y) {
  const int bid = (blockIdx.x & 7) * 64 + (blockIdx.x >> 3);  // 512%8==0
  const int be = bid >> 4, tile = bid & 15;
  const int b = be >> 3, e = be & 7;
  const int bm = tile >> 1, bn = tile & 1;

  const int tid = threadIdx.x, lane = tid & 63, wv = tid >> 6;
  const int wr = wv >> 2, wc = wv & 3;
  const int g16 = lane >> 4, fr = lane & 15;

  const unsigned short* Ag =
      cbp + (size_t)b * NT * NEC + (size_t)(bm * 256) * NEC + e * NC;
  const unsigned short* Bg =
      xT + (size_t)be * NI * NC + (size_t)(bn * 256) * NC;

  __shared__ __align__(16) unsigned short lds[65536];

  f32x4 acc[8][4];
#pragma unroll
  for (int m = 0; m < 8; ++m)
#pragma unroll
    for (int n = 0; n < 4; ++n) acc[m][n] = (f32x4)0.f;

  gemm8_core<NC / 64>(Ag, Bg, NEC, NC, lds, acc);

  const int t0 = bm * 256 + wr * 128;
  const int i0c = bn * 256 + wc * 64;
#pragma unroll
  for (int ii = 0; ii < 8; ++ii) {
#pragma unroll
    for (int j = 0; j < 4; ++j) {
      const int t = t0 + (ii >> 2) * 64 + (ii & 3) * 16 + g16 * 4 + j;
      unsigned short* yp = Y + ((size_t)b * NT + t) * NEI + e * NI + i0c;
#pragma unroll
      for (int n = 0; n < 4; ++n) yp[n * 16 + fr] = f2bf(acc[ii][n][j]);
    }
  }
}

// Stage 2': out[b,t,o] = sum_{ei} Y[b,t,ei] * Wt[o,ei] + bias[o]*S[b,t]
// Per b: M=T=2048, N=O=4096, K=EI=4096. B (Wt) shared across batches.
__global__ __launch_bounds__(512, 2) void k_gemm2q(
    const unsigned short* __restrict__ Y, const unsigned short* __restrict__ Wt,
    const float* __restrict__ bias, const float* __restrict__ S,
    float* __restrict__ out) {
  const int bid = (blockIdx.x & 7) * 64 + (blockIdx.x >> 3);  // 512%8==0
  const int b  = bid >> 7;
  const int bm = (bid >> 4) & 7;
  const int bn = bid & 15;

  const int tid = threadIdx.x, lane = tid & 63, wv = tid >> 6;
  const int wr = wv >> 2, wc = wv & 3;
  const int g16 = lane >> 4, fr = lane & 15;

  const unsigned short* Ag = Y + (size_t)b * NT * NEI + (size_t)(bm * 256) * NEI;
  const unsigned short* Bg = Wt + (size_t)(bn * 256) * NEI;

  __shared__ __align__(16) unsigned short lds[65536];

  f32x4 acc[8][4];
#pragma unroll
  for (int m = 0; m < 8; ++m)
#pragma unroll
    for (int n = 0; n < 4; ++n) acc[m][n] = (f32x4)0.f;

  gemm8_core<NEI / 64>(Ag, Bg, NEI, NEI, lds, acc);

  const int t0 = bm * 256 + wr * 128;
  const int o0 = bn * 256 + wc * 64;
  float bv[4];
#pragma unroll
  for (int n = 0; n < 4; ++n) bv[n] = bias[o0 + n * 16 + fr];
#pragma unroll
  for (int ii = 0; ii < 8; ++ii) {
#pragma unroll
    for (int j = 0; j < 4; ++j) {
      const int t = t0 + (ii >> 2) * 64 + (ii & 3) * 16 + g16 * 4 + j;
      const float sv = S[b * NT + t];
      float* op = out + ((size_t)b * NT + t) * NO + o0;
#pragma unroll
      for (int n = 0; n < 4; ++n) op[n * 16 + fr] = acc[ii][n][j] + bv[n] * sv;
    }
  }
}

// ===========================================================================
// FALLBACK (round-4 verified) — used when ws_size < ~185 MB
// ===========================================================================
__global__ __launch_bounds__(256, 2) void k_gemm1(
    const float* __restrict__ x, const float* __restrict__ W,
    const float* __restrict__ bias, unsigned short* __restrict__ eoT) {
  const int tile = blockIdx.x;
  const int e = blockIdx.y, b = blockIdx.z;
  const int bm = tile >> 2, bn = tile & 3;
  const int tid = threadIdx.x, lane = tid & 63, wv = tid >> 6;
  const int wr = wv >> 1, wc = wv & 1;

  const float* Ag = W + (size_t)e * NO * NI + (size_t)(bm * 128) * NI;
  const float* Bg = x + ((size_t)b * NE + e) * NC * NI + (size_t)(bn * 128) * NI;

  __shared__ __align__(16) unsigned short As[128 * 32];
  __shared__ __align__(16) unsigned short Bs[128 * 32];

  f32x4 acc[4][4];
#pragma unroll
  for (int m = 0; m < 4; ++m)
#pragma unroll
    for (int n = 0; n < 4; ++n) acc[m][n] = (f32x4)0.f;

  for (int k0 = 0; k0 < NI; k0 += 32) {
    __syncthreads();
#pragma unroll
    for (int s = 0; s < 2; ++s) {
      const int q = tid + s * 256;
      const int row = q >> 2, kc = (q & 3) * 8;
      const float* ga = Ag + (size_t)row * NI + k0 + kc;
      float4 a0 = *(const float4*)ga;
      float4 a1 = *(const float4*)(ga + 4);
      *(ushort8*)((char*)As + lds_byte(row, kc * 2)) = cvt8(a0, a1);
      const float* gb = Bg + (size_t)row * NI + k0 + kc;
      float4 b0 = *(const float4*)gb;
      float4 b1 = *(const float4*)(gb + 4);
      *(ushort8*)((char*)Bs + lds_byte(row, kc * 2)) = cvt8(b0, b1);
    }
    __syncthreads();

    const int kb = (lane >> 4) * 16;
    short8 af[4], bfv[4];
#pragma unroll
    for (int m = 0; m < 4; ++m) {
      const int r = wr * 64 + m * 16 + (lane & 15);
      af[m] = *(const short8*)((const char*)As + lds_byte(r, kb));
    }
#pragma unroll
    for (int n = 0; n < 4; ++n) {
      const int r = wc * 64 + n * 16 + (lane & 15);
      bfv[n] = *(const short8*)((const char*)Bs + lds_byte(r, kb));
    }
#pragma unroll
    for (int m = 0; m < 4; ++m)
#pragma unroll
      for (int n = 0; n < 4; ++n)
        acc[m][n] = __builtin_amdgcn_mfma_f32_16x16x32_bf16(
            af[m], bfv[n], acc[m][n], 0, 0, 0);
  }

  const int o0 = bm * 128 + wr * 64;
  const int c0 = bn * 128 + wc * 64;
#pragma unroll
  for (int m = 0; m < 4; ++m) {
#pragma unroll
    for (int j = 0; j < 4; ++j) {
      const int o = o0 + m * 16 + (lane >> 4) * 4 + j;
      const float bvv = bias[o];
      const size_t base = (((size_t)b * NO + o) * NE + e) * NC + c0;
#pragma unroll
      for (int n = 0; n < 4; ++n)
        eoT[base + n * 16 + (lane & 15)] = f2bf(acc[m][n][j] + bvv);
    }
  }
}

__global__ __launch_bounds__(256, 2) void k_gemm2(
    const float* __restrict__ comb, const unsigned short* __restrict__ eoT,
    float* __restrict__ out) {
  const int b = blockIdx.y;
  const int bm = blockIdx.x >> 5;
  const int bn = blockIdx.x & 31;
  const int tid = threadIdx.x, lane = tid & 63, wv = tid >> 6;
  const int wr = wv >> 1, wc = wv & 1;

  const float* Ag = comb + (size_t)b * NT * NEC + (size_t)(bm * 128) * NEC;
  const unsigned short* Bg = eoT + (size_t)b * NO * NEC + (size_t)(bn * 128) * NEC;

  __shared__ __align__(16) unsigned short As[128 * 32];
  __shared__ __align__(16) unsigned short Bs[128 * 32];

  f32x4 acc[4][4];
#pragma unroll
  for (int m = 0; m < 4; ++m)
#pragma unroll
    for (int n = 0; n < 4; ++n) acc[m][n] = (f32x4)0.f;

  for (int k0 = 0; k0 < NEC; k0 += 32) {
    __syncthreads();
#pragma unroll
    for (int s = 0; s < 2; ++s) {
      const int q = tid + s * 256;
      const int row = q >> 2, kc = (q & 3) * 8;
      const float* ga = Ag + (size_t)row * NEC + k0 + kc;
      float4 a0 = *(const float4*)ga;
      float4 a1 = *(const float4*)(ga + 4);
      *(ushort8*)((char*)As + lds_byte(row, kc * 2)) = cvt8(a0, a1);
      ushort8 bvv = *(const ushort8*)(Bg + (size_t)row * NEC + k0 + kc);
      *(ushort8*)((char*)Bs + lds_byte(row, kc * 2)) = bvv;
    }
    __syncthreads();

    const int kb = (lane >> 4) * 16;
    short8 af[4], bfv[4];
#pragma unroll
    for (int m = 0; m < 4; ++m) {
      const int r = wr * 64 + m * 16 + (lane & 15);
      af[m] = *(const short8*)((const char*)As + lds_byte(r, kb));
    }
#pragma unroll
    for (int n = 0; n < 4; ++n) {
      const int r = wc * 64 + n * 16 + (lane & 15);
      bfv[n] = *(const short8*)((const char*)Bs + lds_byte(r, kb));
    }
#pragma unroll
    for (int m = 0; m < 4; ++m)
#pragma unroll
      for (int n = 0; n < 4; ++n)
        acc[m][n] = __builtin_amdgcn_mfma_f32_16x16x32_bf16(
            af[m], bfv[n], acc[m][n], 0, 0, 0);
  }

  const int t0 = bm * 128 + wr * 64;
  const int o0 = bn * 128 + wc * 64;
#pragma unroll
  for (int m = 0; m < 4; ++m) {
#pragma unroll
    for (int j = 0; j < 4; ++j) {
      const int t = t0 + m * 16 + (lane >> 4) * 4 + j;
      float* op = out + ((size_t)b * NT + t) * NO + o0;
#pragma unroll
      for (int n = 0; n < 4; ++n) op[n * 16 + (lane & 15)] = acc[m][n][j];
    }
  }
}

extern "C" void kernel_launch(void* const* d_in, const int* in_sizes, int n_in,
                              void* d_out, int out_size, void* d_ws, size_t ws_size,
                              hipStream_t stream) {
  const float* x    = (const float*)d_in[0];  // [B,E,C,I]
  const float* comb = (const float*)d_in[1];  // [B,T,E,C]
  const float* W    = (const float*)d_in[2];  // [E,O,I]
  const float* bias = (const float*)d_in[3];  // [O]
  float* out = (float*)d_out;                 // [B,T,O]

  // Restructured workspace: Y | cbp | xT | Wt | S
  const size_t Y_ELEMS  = (size_t)NB * NT * NEI;  // 33,554,432
  const size_t C_ELEMS  = (size_t)NB * NT * NEC;  // 33,554,432
  const size_t XT_ELEMS = (size_t)NB * NE * NI * NC;  // 8,388,608
  const size_t WT_ELEMS = (size_t)NO * NE * NI;   // 16,777,216
  const size_t need =
      (Y_ELEMS + C_ELEMS + XT_ELEMS + WT_ELEMS) * 2 + (size_t)NB * NT * 4;

  if (ws_size >= need) {
    unsigned short* Yp  = (unsigned short*)d_ws;
    unsigned short* cbp = Yp + Y_ELEMS;
    unsigned short* xT  = cbp + C_ELEMS;
    unsigned short* Wt  = xT + XT_ELEMS;
    float* S = (float*)(Wt + WT_ELEMS);

    k_cvtT_x<<<2048, 256, 0, stream>>>(x, xT);
    k_cvt_comb<<<NB * NT, 256, 0, stream>>>(comb, cbp, S);
    k_gemm1q<<<512, 512, 0, stream>>>(cbp, xT, Yp);
    k_cvtT_W<<<2048, 256, 0, stream>>>(W, Wt);
    k_gemm2q<<<512, 512, 0, stream>>>(Yp, Wt, bias, S, out);
  } else {
    // Fallback: round-4 verified reg-staged kernels (needs only 134MB)
    unsigned short* eoT = (unsigned short*)d_ws;
    k_gemm1<<<dim3(128, NE, NB), 256, 0, stream>>>(x, W, bias, eoT);
    k_gemm2<<<dim3(512, NB), 256, 0, stream>>>(comb, eoT, out);
  }
}

// Round 13
// 351.382 us; speedup vs baseline: 1.5049x; 1.0086x over previous
//
#include <hip/hip_runtime.h>
#include <hip/hip_bf16.h>
#include <cstdint>

// Problem constants: B,T,E,C,I_E,O = 4,2048,8,512,512,4096
constexpr int NB = 4;
constexpr int NT = 2048;
constexpr int NE = 8;
constexpr int NC = 512;
constexpr int NI = 512;
constexpr int NO = 4096;
constexpr int NEC = NE * NC;   // 4096
constexpr int NEI = NE * NI;   // 4096 (restructured stage-2 K)

typedef __attribute__((ext_vector_type(8))) short short8;
typedef __attribute__((ext_vector_type(8))) unsigned short ushort8;
typedef __attribute__((ext_vector_type(4))) float f32x4;

__device__ __forceinline__ unsigned short f2bf(float f) {
  unsigned int u = __builtin_bit_cast(unsigned int, f);
  u += 0x7FFFu + ((u >> 16) & 1u);
  return (unsigned short)(u >> 16);
}

__device__ __forceinline__ ushort8 cvt8(float4 a, float4 b) {
  ushort8 v;
  v[0] = f2bf(a.x); v[1] = f2bf(a.y); v[2] = f2bf(a.z); v[3] = f2bf(a.w);
  v[4] = f2bf(b.x); v[5] = f2bf(b.y); v[6] = f2bf(b.z); v[7] = f2bf(b.w);
  return v;
}

// swizzle for the fallback 128x32 tiles
__device__ __forceinline__ int lds_byte(int row, int kbyte) {
  return (row * 64 + kbyte) ^ ((row & 6) << 3);
}

__device__ __forceinline__ void gload_lds16(const void* g, void* lds) {
  __builtin_amdgcn_global_load_lds(
      (const __attribute__((address_space(1))) unsigned int*)g,
      (__attribute__((address_space(3))) unsigned int*)lds, 16, 0, 0);
}

// ===========================================================================
// Conversion / permutation passes
// ===========================================================================

// comb f32 [B,T,E,C] -> cbp bf16 (same layout) + S[b*T+t] = row sum (f32)
__global__ __launch_bounds__(256) void k_cvt_comb(
    const float* __restrict__ comb, unsigned short* __restrict__ cbp,
    float* __restrict__ S) {
  const int row = blockIdx.x;  // 8192 rows of 4096
  const float* src = comb + (size_t)row * NEC;
  unsigned short* dst = cbp + (size_t)row * NEC;
  const int tid = threadIdx.x;
  float sum = 0.f;
#pragma unroll
  for (int it = 0; it < 2; ++it) {
    const int i8 = tid + it * 256;
    const float4* s = (const float4*)(src + i8 * 8);
    float4 a = s[0], b4 = s[1];
    *(ushort8*)(dst + i8 * 8) = cvt8(a, b4);
    sum += a.x + a.y + a.z + a.w + b4.x + b4.y + b4.z + b4.w;
  }
  for (int off = 32; off > 0; off >>= 1) sum += __shfl_down(sum, off);
  __shared__ float ws4[4];
  if ((tid & 63) == 0) ws4[tid >> 6] = sum;
  __syncthreads();
  if (tid == 0) S[row] = ws4[0] + ws4[1] + ws4[2] + ws4[3];
}

// x f32 [B,E,C,I] -> xT bf16 [B,E,I,C]  (64x64 LDS-tiled transpose)
__global__ __launch_bounds__(256) void k_cvtT_x(
    const float* __restrict__ x, unsigned short* __restrict__ xT) {
  const int be = blockIdx.x >> 6;    // 32
  const int tile = blockIdx.x & 63;  // 8x8 tiles
  const int c0 = (tile >> 3) * 64, i0 = (tile & 7) * 64;
  const float* src = x + (size_t)be * NC * NI;
  unsigned short* dst = xT + (size_t)be * NI * NC;
  __shared__ unsigned short tl[64][65];
  const int lr = threadIdx.x >> 6, lc = threadIdx.x & 63;
#pragma unroll
  for (int s = 0; s < 16; ++s) {
    const int c = s * 4 + lr;
    tl[c][lc] = f2bf(src[(size_t)(c0 + c) * NI + i0 + lc]);
  }
  __syncthreads();
#pragma unroll
  for (int s = 0; s < 16; ++s) {
    const int i = s * 4 + lr;
    dst[(size_t)(i0 + i) * NC + c0 + lc] = tl[lc][i];
  }
}

// W f32 [E,O,I] -> Wt bf16 [O,E,I]  (coalesced both sides; i innermost)
__global__ __launch_bounds__(256) void k_cvtT_W(
    const float* __restrict__ W, unsigned short* __restrict__ Wt) {
  const size_t n8 = (size_t)NE * NO * NI / 8;  // 2,097,152
  size_t idx = (size_t)blockIdx.x * 256 + threadIdx.x;
  const size_t stride = (size_t)gridDim.x * 256;
  for (; idx < n8; idx += stride) {
    const int i8 = (int)(idx & (NI / 8 - 1));
    const size_t eo = idx >> 6;          // e*O + o
    const int e = (int)(eo >> 12);
    const int o = (int)(eo & 4095);
    const float4* s = (const float4*)(W + eo * NI + i8 * 8);
    float4 a = s[0], b4 = s[1];
    *(ushort8*)(Wt + ((size_t)o * NE + e) * NI + i8 * 8) = cvt8(a, b4);
  }
}

// ===========================================================================
// 256x256 4-merged-phase READ-AHEAD pipeline core.
// Identical op order to the r11-verified 8-phase schedule with the mid-pair
// barriers removed (8 BAR -> 4 BAR per 2 K-tiles) and vmcnt re-derived:
// one VM4 per merged phase, after the 2nd STG. Steady-state in-flight at
// each VM4 is 8 -> it proves the PREVIOUS phase's STG pair; coverage chain
// (VM <= BAR <= read) verified for all 8 slots; prologue uses vmcnt(4) so
// M1's second-half reads (A01,B01) are barrier-proven. Restage of every
// slot is >=1 BAR after its last reader's lgkm drain. LG4/LG8 unchanged.
// Bank pattern (PMC-verified 0 conflicts): read chunk = g16 ^ ((fr>>1)&3);
// source chunk pre-swizzled (lane&3)^((lane>>3)&3).
// ===========================================================================
template <int NKT>
__device__ __forceinline__ void gemm8_core(
    const unsigned short* __restrict__ Ag,
    const unsigned short* __restrict__ Bg,
    const int ldkA, const int ldkB, unsigned short* lds, f32x4 (&acc)[8][4]) {
  const int tid = threadIdx.x, lane = tid & 63, wv = tid >> 6;
  const int wr = wv >> 2, wc = wv & 3;
  const int g16 = lane >> 4;
  const int fr  = lane & 15;
  const int pc  = (g16 ^ ((fr >> 1) & 3)) << 4;

  const int scg = (lane & 3) ^ ((lane >> 3) & 3);
  const size_t srow0A = (size_t)(wv * 16 + (lane >> 2)) * ldkA + scg * 8;
  const size_t srow0B = (size_t)(wv * 16 + (lane >> 2)) * ldkB + scg * 8;
  const size_t srstA = (size_t)128 * ldkA;
  const size_t srstB = (size_t)128 * ldkB;
  const int sdst0 = wv * 512;

#define ASLOT(D, KH) ((D) * 16384 + (KH) * 8192)
#define BSLOT(D, KH) (32768 + (D) * 16384 + (KH) * 8192)
#define STG(PTR, SR0, SRST, SLOT, KT, KH)                                  \
  {                                                                        \
    const unsigned short* _g = (PTR) + (SR0) + (size_t)(KT) * 64 + (KH) * 32; \
    gload_lds16(_g, lds + (SLOT) + sdst0);                                 \
    gload_lds16(_g + (SRST), lds + (SLOT) + 4096 + sdst0);                 \
  }
#define RD8(SLOT, R) \
  (*(const short8*)((const char*)lds + (SLOT) * 2 + (R) * 64 + pc))

  short8 afA[4], afB[4], bfA[4], bfB[4];

#define LDA4(SET, D, KH, MH)                                        \
  _Pragma("unroll") for (int m = 0; m < 4; ++m) {                   \
    SET[m] = RD8(ASLOT(D, KH), wr * 128 + (MH) * 64 + m * 16 + fr); \
  }
#define LDB4(SET, D, KH)                                            \
  _Pragma("unroll") for (int n = 0; n < 4; ++n) {                   \
    SET[n] = RD8(BSLOT(D, KH), wc * 64 + n * 16 + fr);              \
  }
#define MFMAQ(ASET, BSET, MH)                                        \
  __builtin_amdgcn_s_setprio(1);                                     \
  _Pragma("unroll") for (int m = 0; m < 4; ++m)                      \
  _Pragma("unroll") for (int n = 0; n < 4; ++n) {                    \
    acc[(MH) * 4 + m][n] = __builtin_amdgcn_mfma_f32_16x16x32_bf16(  \
        ASET[m], BSET[n], acc[(MH) * 4 + m][n], 0, 0, 0);            \
  }                                                                  \
  __builtin_amdgcn_s_setprio(0);
#define LG4()                                          \
  asm volatile("s_waitcnt lgkmcnt(4)" ::: "memory");   \
  __builtin_amdgcn_sched_barrier(0)
#define LG8()                                          \
  asm volatile("s_waitcnt lgkmcnt(8)" ::: "memory");   \
  __builtin_amdgcn_sched_barrier(0)
#define VM4() asm volatile("s_waitcnt vmcnt(4)" ::: "memory")
#define BAR() __builtin_amdgcn_s_barrier()

  // prologue: stage A00,B00,A01,B01,A10,B10; prove A00..B01 (vmcnt(4));
  // BAR; issue rd(M1-first) = A00,B00 fragments.
  STG(Ag, srow0A, srstA, ASLOT(0, 0), 0, 0);
  STG(Bg, srow0B, srstB, BSLOT(0, 0), 0, 0);
  STG(Ag, srow0A, srstA, ASLOT(0, 1), 0, 1);
  STG(Bg, srow0B, srstB, BSLOT(0, 1), 0, 1);
  STG(Ag, srow0A, srstA, ASLOT(1, 0), 1, 0);
  STG(Bg, srow0B, srstB, BSLOT(1, 0), 1, 0);
  asm volatile("s_waitcnt vmcnt(4)" ::: "memory");
  BAR();
  LDA4(afA, 0, 0, 0); LDB4(bfA, 0, 0);

  for (int it = 0; it < NKT / 2; ++it) {
    const int k1 = (2 * it + 1) & (NKT - 1);
    const int k2 = (2 * it + 2) & (NKT - 1);
    const int k3 = (2 * it + 3) & (NKT - 1);
    // M1: (d0,k0,m0)+(d0,k0,m1); stages A11,B11<-k1; VM4 proves A10,B10
    STG(Ag, srow0A, srstA, ASLOT(1, 1), k1, 1);
    LDA4(afB, 0, 0, 1);
    LG4();
    MFMAQ(afA, bfA, 0);
    STG(Bg, srow0B, srstB, BSLOT(1, 1), k1, 1);
    VM4();
    LDA4(afA, 0, 1, 0); LDB4(bfB, 0, 1);
    LG8();
    MFMAQ(afB, bfA, 1);
    BAR();
    // M2: (d0,k1,m0)+(d0,k1,m1); stages A00,B00<-k2; VM4 proves A11,B11
    STG(Ag, srow0A, srstA, ASLOT(0, 0), k2, 0);
    LDA4(afB, 0, 1, 1);
    LG4();
    MFMAQ(afA, bfB, 0);
    STG(Bg, srow0B, srstB, BSLOT(0, 0), k2, 0);
    VM4();
    LDA4(afA, 1, 0, 0); LDB4(bfA, 1, 0);
    LG8();
    MFMAQ(afB, bfB, 1);
    BAR();
    // M3: (d1,k0,m0)+(d1,k0,m1); stages A01,B01<-k2; VM4 proves A00,B00
    STG(Ag, srow0A, srstA, ASLOT(0, 1), k2, 1);
    LDA4(afB, 1, 0, 1);
    LG4();
    MFMAQ(afA, bfA, 0);
    STG(Bg, srow0B, srstB, BSLOT(0, 1), k2, 1);
    VM4();
    LDA4(afA, 1, 1, 0); LDB4(bfB, 1, 1);
    LG8();
    MFMAQ(afB, bfA, 1);
    BAR();
    // M4: (d1,k1,m0)+(d1,k1,m1); stages A10,B10<-k3; VM4 proves A01,B01
    STG(Ag, srow0A, srstA, ASLOT(1, 0), k3, 0);
    LDA4(afB, 1, 1, 1);
    LG4();
    MFMAQ(afA, bfB, 0);
    STG(Bg, srow0B, srstB, BSLOT(1, 0), k3, 0);
    VM4();
    LDA4(afA, 0, 0, 0); LDB4(bfA, 0, 0);
    LG8();
    MFMAQ(afB, bfB, 1);
    BAR();
  }
  asm volatile("s_waitcnt vmcnt(0) lgkmcnt(0)" ::: "memory");
#undef ASLOT
#undef BSLOT
#undef STG
#undef RD8
#undef LDA4
#undef LDB4
#undef MFMAQ
#undef LG4
#undef LG8
#undef VM4
#undef BAR
}

// Stage 1': Y[b,t,e*512+i] = sum_c comb[b,t,e,c] * xT[b,e,i,c]   (bf16 out)
__global__ __launch_bounds__(512, 2) void k_gemm1q(
    const unsigned short* __restrict__ cbp, const unsigned short* __restrict__ xT,
    unsigned short* __restrict__ Y) {
  const int bid = (blockIdx.x & 7) * 64 + (blockIdx.x >> 3);  // 512%8==0
  const int be = bid >> 4, tile = bid & 15;
  const int b = be >> 3, e = be & 7;
  const int bm = tile >> 1, bn = tile & 1;

  const int tid = threadIdx.x, lane = tid & 63, wv = tid >> 6;
  const int wr = wv >> 2, wc = wv & 3;
  const int g16 = lane >> 4, fr = lane & 15;

  const unsigned short* Ag =
      cbp + (size_t)b * NT * NEC + (size_t)(bm * 256) * NEC + e * NC;
  const unsigned short* Bg =
      xT + (size_t)be * NI * NC + (size_t)(bn * 256) * NC;

  __shared__ __align__(16) unsigned short lds[65536];

  f32x4 acc[8][4];
#pragma unroll
  for (int m = 0; m < 8; ++m)
#pragma unroll
    for (int n = 0; n < 4; ++n) acc[m][n] = (f32x4)0.f;

  gemm8_core<NC / 64>(Ag, Bg, NEC, NC, lds, acc);

  const int t0 = bm * 256 + wr * 128;
  const int i0c = bn * 256 + wc * 64;
#pragma unroll
  for (int ii = 0; ii < 8; ++ii) {
#pragma unroll
    for (int j = 0; j < 4; ++j) {
      const int t = t0 + (ii >> 2) * 64 + (ii & 3) * 16 + g16 * 4 + j;
      unsigned short* yp = Y + ((size_t)b * NT + t) * NEI + e * NI + i0c;
#pragma unroll
      for (int n = 0; n < 4; ++n) yp[n * 16 + fr] = f2bf(acc[ii][n][j]);
    }
  }
}

// Stage 2': out[b,t,o] = sum_{ei} Y[b,t,ei] * Wt[o,ei] + bias[o]*S[b,t]
__global__ __launch_bounds__(512, 2) void k_gemm2q(
    const unsigned short* __restrict__ Y, const unsigned short* __restrict__ Wt,
    const float* __restrict__ bias, const float* __restrict__ S,
    float* __restrict__ out) {
  const int bid = (blockIdx.x & 7) * 64 + (blockIdx.x >> 3);  // 512%8==0
  const int b  = bid >> 7;
  const int bm = (bid >> 4) & 7;
  const int bn = bid & 15;

  const int tid = threadIdx.x, lane = tid & 63, wv = tid >> 6;
  const int wr = wv >> 2, wc = wv & 3;
  const int g16 = lane >> 4, fr = lane & 15;

  const unsigned short* Ag = Y + (size_t)b * NT * NEI + (size_t)(bm * 256) * NEI;
  const unsigned short* Bg = Wt + (size_t)(bn * 256) * NEI;

  __shared__ __align__(16) unsigned short lds[65536];

  f32x4 acc[8][4];
#pragma unroll
  for (int m = 0; m < 8; ++m)
#pragma unroll
    for (int n = 0; n < 4; ++n) acc[m][n] = (f32x4)0.f;

  gemm8_core<NEI / 64>(Ag, Bg, NEI, NEI, lds, acc);

  const int t0 = bm * 256 + wr * 128;
  const int o0 = bn * 256 + wc * 64;
  float bv[4];
#pragma unroll
  for (int n = 0; n < 4; ++n) bv[n] = bias[o0 + n * 16 + fr];
#pragma unroll
  for (int ii = 0; ii < 8; ++ii) {
#pragma unroll
    for (int j = 0; j < 4; ++j) {
      const int t = t0 + (ii >> 2) * 64 + (ii & 3) * 16 + g16 * 4 + j;
      const float sv = S[b * NT + t];
      float* op = out + ((size_t)b * NT + t) * NO + o0;
#pragma unroll
      for (int n = 0; n < 4; ++n) op[n * 16 + fr] = acc[ii][n][j] + bv[n] * sv;
    }
  }
}

// ===========================================================================
// FALLBACK (round-4 verified) — used when ws_size < ~185 MB
// ===========================================================================
__global__ __launch_bounds__(256, 2) void k_gemm1(
    const float* __restrict__ x, const float* __restrict__ W,
    const float* __restrict__ bias, unsigned short* __restrict__ eoT) {
  const int tile = blockIdx.x;
  const int e = blockIdx.y, b = blockIdx.z;
  const int bm = tile >> 2, bn = tile & 3;
  const int tid = threadIdx.x, lane = tid & 63, wv = tid >> 6;
  const int wr = wv >> 1, wc = wv & 1;

  const float* Ag = W + (size_t)e * NO * NI + (size_t)(bm * 128) * NI;
  const float* Bg = x + ((size_t)b * NE + e) * NC * NI + (size_t)(bn * 128) * NI;

  __shared__ __align__(16) unsigned short As[128 * 32];
  __shared__ __align__(16) unsigned short Bs[128 * 32];

  f32x4 acc[4][4];
#pragma unroll
  for (int m = 0; m < 4; ++m)
#pragma unroll
    for (int n = 0; n < 4; ++n) acc[m][n] = (f32x4)0.f;

  for (int k0 = 0; k0 < NI; k0 += 32) {
    __syncthreads();
#pragma unroll
    for (int s = 0; s < 2; ++s) {
      const int q = tid + s * 256;
      const int row = q >> 2, kc = (q & 3) * 8;
      const float* ga = Ag + (size_t)row * NI + k0 + kc;
      float4 a0 = *(const float4*)ga;
      float4 a1 = *(const float4*)(ga + 4);
      *(ushort8*)((char*)As + lds_byte(row, kc * 2)) = cvt8(a0, a1);
      const float* gb = Bg + (size_t)row * NI + k0 + kc;
      float4 b0 = *(const float4*)gb;
      float4 b1 = *(const float4*)(gb + 4);
      *(ushort8*)((char*)Bs + lds_byte(row, kc * 2)) = cvt8(b0, b1);
    }
    __syncthreads();

    const int kb = (lane >> 4) * 16;
    short8 af[4], bfv[4];
#pragma unroll
    for (int m = 0; m < 4; ++m) {
      const int r = wr * 64 + m * 16 + (lane & 15);
      af[m] = *(const short8*)((const char*)As + lds_byte(r, kb));
    }
#pragma unroll
    for (int n = 0; n < 4; ++n) {
      const int r = wc * 64 + n * 16 + (lane & 15);
      bfv[n] = *(const short8*)((const char*)Bs + lds_byte(r, kb));
    }
#pragma unroll
    for (int m = 0; m < 4; ++m)
#pragma unroll
      for (int n = 0; n < 4; ++n)
        acc[m][n] = __builtin_amdgcn_mfma_f32_16x16x32_bf16(
            af[m], bfv[n], acc[m][n], 0, 0, 0);
  }

  const int o0 = bm * 128 + wr * 64;
  const int c0 = bn * 128 + wc * 64;
#pragma unroll
  for (int m = 0; m < 4; ++m) {
#pragma unroll
    for (int j = 0; j < 4; ++j) {
      const int o = o0 + m * 16 + (lane >> 4) * 4 + j;
      const float bvv = bias[o];
      const size_t base = (((size_t)b * NO + o) * NE + e) * NC + c0;
#pragma unroll
      for (int n = 0; n < 4; ++n)
        eoT[base + n * 16 + (lane & 15)] = f2bf(acc[m][n][j] + bvv);
    }
  }
}

__global__ __launch_bounds__(256, 2) void k_gemm2(
    const float* __restrict__ comb, const unsigned short* __restrict__ eoT,
    float* __restrict__ out) {
  const int b = blockIdx.y;
  const int bm = blockIdx.x >> 5;
  const int bn = blockIdx.x & 31;
  const int tid = threadIdx.x, lane = tid & 63, wv = tid >> 6;
  const int wr = wv >> 1, wc = wv & 1;

  const float* Ag = comb + (size_t)b * NT * NEC + (size_t)(bm * 128) * NEC;
  const unsigned short* Bg = eoT + (size_t)b * NO * NEC + (size_t)(bn * 128) * NEC;

  __shared__ __align__(16) unsigned short As[128 * 32];
  __shared__ __align__(16) unsigned short Bs[128 * 32];

  f32x4 acc[4][4];
#pragma unroll
  for (int m = 0; m < 4; ++m)
#pragma unroll
    for (int n = 0; n < 4; ++n) acc[m][n] = (f32x4)0.f;

  for (int k0 = 0; k0 < NEC; k0 += 32) {
    __syncthreads();
#pragma unroll
    for (int s = 0; s < 2; ++s) {
      const int q = tid + s * 256;
      const int row = q >> 2, kc = (q & 3) * 8;
      const float* ga = Ag + (size_t)row * NEC + k0 + kc;
      float4 a0 = *(const float4*)ga;
      float4 a1 = *(const float4*)(ga + 4);
      *(ushort8*)((char*)As + lds_byte(row, kc * 2)) = cvt8(a0, a1);
      ushort8 bvv = *(const ushort8*)(Bg + (size_t)row * NEC + k0 + kc);
      *(ushort8*)((char*)Bs + lds_byte(row, kc * 2)) = bvv;
    }
    __syncthreads();

    const int kb = (lane >> 4) * 16;
    short8 af[4], bfv[4];
#pragma unroll
    for (int m = 0; m < 4; ++m) {
      const int r = wr * 64 + m * 16 + (lane & 15);
      af[m] = *(const short8*)((const char*)As + lds_byte(r, kb));
    }
#pragma unroll
    for (int n = 0; n < 4; ++n) {
      const int r = wc * 64 + n * 16 + (lane & 15);
      bfv[n] = *(const short8*)((const char*)Bs + lds_byte(r, kb));
    }
#pragma unroll
    for (int m = 0; m < 4; ++m)
#pragma unroll
      for (int n = 0; n < 4; ++n)
        acc[m][n] = __builtin_amdgcn_mfma_f32_16x16x32_bf16(
            af[m], bfv[n], acc[m][n], 0, 0, 0);
  }

  const int t0 = bm * 128 + wr * 64;
  const int o0 = bn * 128 + wc * 64;
#pragma unroll
  for (int m = 0; m < 4; ++m) {
#pragma unroll
    for (int j = 0; j < 4; ++j) {
      const int t = t0 + m * 16 + (lane >> 4) * 4 + j;
      float* op = out + ((size_t)b * NT + t) * NO + o0;
#pragma unroll
      for (int n = 0; n < 4; ++n) op[n * 16 + (lane & 15)] = acc[m][n][j];
    }
  }
}

extern "C" void kernel_launch(void* const* d_in, const int* in_sizes, int n_in,
                              void* d_out, int out_size, void* d_ws, size_t ws_size,
                              hipStream_t stream) {
  const float* x    = (const float*)d_in[0];  // [B,E,C,I]
  const float* comb = (const float*)d_in[1];  // [B,T,E,C]
  const float* W    = (const float*)d_in[2];  // [E,O,I]
  const float* bias = (const float*)d_in[3];  // [O]
  float* out = (float*)d_out;                 // [B,T,O]

  // Restructured workspace: Y | cbp | xT | Wt | S
  const size_t Y_ELEMS  = (size_t)NB * NT * NEI;  // 33,554,432
  const size_t C_ELEMS  = (size_t)NB * NT * NEC;  // 33,554,432
  const size_t XT_ELEMS = (size_t)NB * NE * NI * NC;  // 8,388,608
  const size_t WT_ELEMS = (size_t)NO * NE * NI;   // 16,777,216
  const size_t need =
      (Y_ELEMS + C_ELEMS + XT_ELEMS + WT_ELEMS) * 2 + (size_t)NB * NT * 4;

  if (ws_size >= need) {
    unsigned short* Yp  = (unsigned short*)d_ws;
    unsigned short* cbp = Yp + Y_ELEMS;
    unsigned short* xT  = cbp + C_ELEMS;
    unsigned short* Wt  = xT + XT_ELEMS;
    float* S = (float*)(Wt + WT_ELEMS);

    k_cvtT_x<<<2048, 256, 0, stream>>>(x, xT);
    k_cvt_comb<<<NB * NT, 256, 0, stream>>>(comb, cbp, S);
    k_gemm1q<<<512, 512, 0, stream>>>(cbp, xT, Yp);
    k_cvtT_W<<<2048, 256, 0, stream>>>(W, Wt);
    k_gemm2q<<<512, 512, 0, stream>>>(Yp, Wt, bias, S, out);
  } else {
    // Fallback: round-4 verified reg-staged kernels (needs only 134MB)
    unsigned short* eoT = (unsigned short*)d_ws;
    k_gemm1<<<dim3(128, NE, NB), 256, 0, stream>>>(x, W, bias, eoT);
    k_gemm2<<<dim3(512, NB), 256, 0, stream>>>(comb, eoT, out);
  }
}